// Round 5
// baseline (1021.057 us; speedup 1.0000x reference)
//
#include <hip/hip_runtime.h>

#define NN 100000
#define NE 1600000
#define FI 128
#define FH 64
#define FO 40
#define NH (NN * FH)     // 6,400,000 mask elements

// ---------------- Threefry-2x32, key = (0, 42)  (jax.random.key(42)) --------
__device__ __forceinline__ unsigned rotl32(unsigned v, unsigned r) {
    return (v << r) | (v >> (32u - r));
}

// full threefry2x32 with key (0,42): returns both output words
__device__ __forceinline__ void threefry_0_42(unsigned x0, unsigned x1,
                                              unsigned& o0, unsigned& o1) {
    const unsigned k0 = 0u, k1 = 42u;
    const unsigned k2 = 0x1BD11BDAu ^ k0 ^ k1;
    x0 += k0; x1 += k1;
#define TFR(r) { x0 += x1; x1 = rotl32(x1, r); x1 ^= x0; }
    TFR(13) TFR(15) TFR(26) TFR(6)   x0 += k1; x1 += k2 + 1u;
    TFR(17) TFR(29) TFR(16) TFR(24)  x0 += k2; x1 += k0 + 2u;
    TFR(13) TFR(15) TFR(26) TFR(6)   x0 += k0; x1 += k1 + 3u;
    TFR(17) TFR(29) TFR(16) TFR(24)  x0 += k1; x1 += k2 + 4u;
    TFR(13) TFR(15) TFR(26) TFR(6)   x0 += k2; x1 += k0 + 5u;
#undef TFR
    o0 = x0; o1 = x1;
}

// ---------------- degree count --------------------------------------------
__global__ __launch_bounds__(256) void k_deg(const int* __restrict__ ei, float* __restrict__ deg) {
    int i = blockIdx.x * blockDim.x + threadIdx.x;
    int stride = gridDim.x * blockDim.x;
    for (; i < NE; i += stride) {
        atomicAdd(&deg[ei[NE + i]], 1.0f);   // dst
    }
}

// deg -> 1/sqrt(deg+1) in place
__global__ __launch_bounds__(256) void k_inv(float* __restrict__ deg) {
    int i = blockIdx.x * blockDim.x + threadIdx.x;
    if (i < NN) deg[i] = 1.0f / sqrtf(deg[i] + 1.0f);
}

// ---------------- GEMM1: h0[N,64] = x[N,128] @ W1[128,64] ------------------
__global__ __launch_bounds__(256) void k_gemm1(const float* __restrict__ x,
                                               const float* __restrict__ W1,
                                               float* __restrict__ h0) {
    __shared__ float w[FI * FH];  // 32 KB
    int t = threadIdx.x;
    for (int i = t; i < FI * FH; i += 256) w[i] = W1[i];
    __syncthreads();
    int wave = t >> 6, lane = t & 63;
    int row = blockIdx.x * 4 + wave;  // grid = NN/4 = 25000 exactly
    float xlo = x[row * FI + lane];
    float xhi = x[row * FI + 64 + lane];
    float acc = 0.f;
#pragma unroll
    for (int c = 0; c < 64; ++c) {
        float xv = __shfl(xlo, c, 64);
        acc = fmaf(xv, w[c * FH + lane], acc);
    }
#pragma unroll
    for (int c = 0; c < 64; ++c) {
        float xv = __shfl(xhi, c, 64);
        acc = fmaf(xv, w[(64 + c) * FH + lane], acc);
    }
    h0[row * FH + lane] = acc;
}

// ---------------- self-loop init: agg[i] = h0[i] * inv[row]^2 --------------
__global__ __launch_bounds__(256) void k_self1(const float* __restrict__ h0,
                                               const float* __restrict__ inv,
                                               float* __restrict__ agg) {
    int i = blockIdx.x * blockDim.x + threadIdx.x;
    int stride = gridDim.x * blockDim.x;
    for (; i < NH; i += stride) {
        float s = inv[i >> 6];
        agg[i] = h0[i] * s * s;
    }
}

// ---------------- scatter layer1: wave per edge, 64 features ---------------
__global__ __launch_bounds__(256) void k_scatter1(const int* __restrict__ ei,
                                                  const float* __restrict__ inv,
                                                  const float* __restrict__ h0,
                                                  float* __restrict__ agg) {
    int lane = threadIdx.x & 63;
    int wid = (blockIdx.x * blockDim.x + threadIdx.x) >> 6;
    int nw = (gridDim.x * blockDim.x) >> 6;
    for (int e = wid; e < NE; e += nw) {
        int s = ei[e];
        int d = ei[NE + e];
        float norm = inv[s] * inv[d];
        float v = h0[s * FH + lane] * norm;
        atomicAdd(&agg[d * FH + lane], v);
    }
}

// ---------------- bias + relu + dropout (partitionable f32 threefry) -------
// jax_threefry_partitionable=True, x64 OFF -> uniform(float32):
//   per-element uint64 counter i -> (x0,x1) = (0, i)
//   (o0,o1) = threefry(key, 0, i); bits32 = o0 ^ o1   (XOR fold for width<=32)
//   keep iff u<0.5 iff bit31(bits32)==0; kept value scaled by 1/keep = 2
__global__ __launch_bounds__(256) void k_bias_relu_drop(float* __restrict__ agg,
                                                        const float* __restrict__ b1) {
    int i = blockIdx.x * blockDim.x + threadIdx.x;
    int stride = gridDim.x * blockDim.x;
    for (; i < NH; i += stride) {
        unsigned o0, o1;
        threefry_0_42(0u, (unsigned)i, o0, o1);
        unsigned w = o0 ^ o1;
        float v = fmaxf(agg[i] + b1[i & 63], 0.f);
        agg[i] = (w >> 31) ? 0.f : v * 2.f;
    }
}

// ---------------- GEMM2: h2[N,40] = h[N,64] @ W2[64,40] --------------------
#define W2PAD (FH * FO + 64)
__global__ __launch_bounds__(256) void k_gemm2(const float* __restrict__ h,
                                               const float* __restrict__ W2,
                                               float* __restrict__ h2) {
    __shared__ float w[W2PAD];
    int t = threadIdx.x;
    for (int i = t; i < FH * FO; i += 256) w[i] = W2[i];
    for (int i = FH * FO + t; i < W2PAD; i += 256) w[i] = 0.f;
    __syncthreads();
    int wave = t >> 6, lane = t & 63;
    int row = blockIdx.x * 4 + wave;  // grid = 25000 exactly
    float hv = h[row * FH + lane];
    float acc = 0.f;
#pragma unroll
    for (int c = 0; c < FH; ++c) {
        float xv = __shfl(hv, c, 64);
        acc = fmaf(xv, w[c * FO + lane], acc);  // lanes >=40 read pad, discarded
    }
    if (lane < FO) h2[row * FO + lane] = acc;
}

// ---------------- out init: out = h2 * inv^2 + b2 --------------------------
__global__ __launch_bounds__(256) void k_self2(const float* __restrict__ h2,
                                               const float* __restrict__ inv,
                                               const float* __restrict__ b2,
                                               float* __restrict__ out) {
    int i = blockIdx.x * blockDim.x + threadIdx.x;
    int stride = gridDim.x * blockDim.x;
    for (; i < NN * FO; i += stride) {
        int row = i / FO;
        int col = i - row * FO;
        float s = inv[row];
        out[i] = h2[i] * s * s + b2[col];
    }
}

// ---------------- scatter layer2: wave per edge, 40 features ---------------
__global__ __launch_bounds__(256) void k_scatter2(const int* __restrict__ ei,
                                                  const float* __restrict__ inv,
                                                  const float* __restrict__ h2,
                                                  float* __restrict__ out) {
    int lane = threadIdx.x & 63;
    int wid = (blockIdx.x * blockDim.x + threadIdx.x) >> 6;
    int nw = (gridDim.x * blockDim.x) >> 6;
    for (int e = wid; e < NE; e += nw) {
        int s = ei[e];
        int d = ei[NE + e];
        float norm = inv[s] * inv[d];
        if (lane < FO) {
            float v = h2[s * FO + lane] * norm;
            atomicAdd(&out[d * FO + lane], v);
        }
    }
}

extern "C" void kernel_launch(void* const* d_in, const int* in_sizes, int n_in,
                              void* d_out, int out_size, void* d_ws, size_t ws_size,
                              hipStream_t stream) {
    const float* x  = (const float*)d_in[0];
    const int*   ei = (const int*)d_in[1];   // int32 [2, NE]: src = ei[e], dst = ei[NE+e]
    const float* W1 = (const float*)d_in[2];
    const float* b1 = (const float*)d_in[3];
    const float* W2 = (const float*)d_in[4];
    const float* b2 = (const float*)d_in[5];
    float* out = (float*)d_out;

    char* ws = (char*)d_ws;
    float* inv  = (float*)ws;                             // NN floats = 0.4 MB
    float* h0   = (float*)(ws + (size_t)(1 << 20));       // NN*64 floats = 25.6 MB
    float* agg1 = (float*)(ws + (size_t)(27 << 20));      // NN*64 floats = 25.6 MB
    float* h2   = h0;                                     // reuse (NN*40)

    hipMemsetAsync(inv, 0, NN * sizeof(float), stream);

    k_deg<<<1024, 256, 0, stream>>>(ei, inv);
    k_inv<<<(NN + 255) / 256, 256, 0, stream>>>(inv);

    k_gemm1<<<NN / 4, 256, 0, stream>>>(x, W1, h0);
    k_self1<<<2048, 256, 0, stream>>>(h0, inv, agg1);
    k_scatter1<<<4096, 256, 0, stream>>>(ei, inv, h0, agg1);
    k_bias_relu_drop<<<2048, 256, 0, stream>>>(agg1, b1);

    k_gemm2<<<NN / 4, 256, 0, stream>>>(agg1, W2, h2);
    k_self2<<<2048, 256, 0, stream>>>(h2, inv, b2, out);
    k_scatter2<<<4096, 256, 0, stream>>>(ei, inv, h2, out);
}

// Round 6
// 711.425 us; speedup vs baseline: 1.4352x; 1.4352x over previous
//
#include <hip/hip_runtime.h>

#define NN 100000
#define NE 1600000
#define FI 128
#define FH 64
#define FO 40
#define NH (NN * FH)            // 6,400,000 mask elements
#define NB ((NN + 255) / 256)   // 391 scan blocks

// ---------------- Threefry-2x32, key = (0, 42) -----------------------------
__device__ __forceinline__ unsigned rotl32(unsigned v, unsigned r) {
    return (v << r) | (v >> (32u - r));
}

__device__ __forceinline__ void threefry_0_42(unsigned x0, unsigned x1,
                                              unsigned& o0, unsigned& o1) {
    const unsigned k0 = 0u, k1 = 42u;
    const unsigned k2 = 0x1BD11BDAu ^ k0 ^ k1;
    x0 += k0; x1 += k1;
#define TFR(r) { x0 += x1; x1 = rotl32(x1, r); x1 ^= x0; }
    TFR(13) TFR(15) TFR(26) TFR(6)   x0 += k1; x1 += k2 + 1u;
    TFR(17) TFR(29) TFR(16) TFR(24)  x0 += k2; x1 += k0 + 2u;
    TFR(13) TFR(15) TFR(26) TFR(6)   x0 += k0; x1 += k1 + 3u;
    TFR(17) TFR(29) TFR(16) TFR(24)  x0 += k1; x1 += k2 + 4u;
    TFR(13) TFR(15) TFR(26) TFR(6)   x0 += k2; x1 += k0 + 5u;
#undef TFR
    o0 = x0; o1 = x1;
}

// ---------------- degree count (int) ---------------------------------------
__global__ __launch_bounds__(256) void k_count(const int* __restrict__ ei,
                                               int* __restrict__ cnt) {
    int i = blockIdx.x * blockDim.x + threadIdx.x;
    int stride = gridDim.x * blockDim.x;
    for (; i < NE; i += stride) atomicAdd(&cnt[ei[NE + i]], 1);
}

// ---------------- 3-kernel exclusive scan ----------------------------------
__global__ __launch_bounds__(256) void k_scanA(const int* __restrict__ cnt,
                                               int* __restrict__ offs,
                                               int* __restrict__ bsum) {
    __shared__ int sh[256];
    int t = threadIdx.x, g = blockIdx.x * 256 + t;
    int v = (g < NN) ? cnt[g] : 0;
    sh[t] = v;
    __syncthreads();
    for (int off = 1; off < 256; off <<= 1) {
        int u = (t >= off) ? sh[t - off] : 0;
        __syncthreads();
        sh[t] += u;
        __syncthreads();
    }
    if (g < NN) offs[g] = sh[t] - v;               // exclusive within block
    if (t == 255) bsum[blockIdx.x] = sh[255];      // block total
}

__global__ __launch_bounds__(512) void k_scanB(int* __restrict__ bsum) {
    __shared__ int sh[512];
    int t = threadIdx.x;
    int v = (t < NB) ? bsum[t] : 0;
    sh[t] = v;
    __syncthreads();
    for (int off = 1; off < 512; off <<= 1) {
        int u = (t >= off) ? sh[t - off] : 0;
        __syncthreads();
        sh[t] += u;
        __syncthreads();
    }
    if (t < NB) bsum[t] = sh[t] - v;               // exclusive block offsets
}

__global__ __launch_bounds__(256) void k_scanC(int* __restrict__ offs,
                                               const int* __restrict__ bsum,
                                               int* __restrict__ cursor) {
    int g = blockIdx.x * 256 + threadIdx.x;
    if (g < NN) {
        int o = offs[g] + bsum[blockIdx.x];
        offs[g] = o;
        cursor[g] = o;
    }
}

// ---------------- inv = rsqrt(cnt + 1) -------------------------------------
__global__ __launch_bounds__(256) void k_inv(const int* __restrict__ cnt,
                                             float* __restrict__ inv) {
    int i = blockIdx.x * blockDim.x + threadIdx.x;
    if (i < NN) inv[i] = rsqrtf((float)cnt[i] + 1.0f);
}

// ---------------- CSR fill: bucket src id + src weight by dst --------------
__global__ __launch_bounds__(256) void k_fill(const int* __restrict__ ei,
                                              const float* __restrict__ inv,
                                              int* __restrict__ cursor,
                                              int* __restrict__ csr_s,
                                              float* __restrict__ csr_w) {
    int i = blockIdx.x * blockDim.x + threadIdx.x;
    int stride = gridDim.x * blockDim.x;
    for (; i < NE; i += stride) {
        int s = ei[i];
        int d = ei[NE + i];
        int pos = atomicAdd(&cursor[d], 1);
        csr_s[pos] = s;
        csr_w[pos] = inv[s];
    }
}

// ---------------- GEMM1: h0[N,64] = x[N,128] @ W1[128,64] ------------------
__global__ __launch_bounds__(256) void k_gemm1(const float* __restrict__ x,
                                               const float* __restrict__ W1,
                                               float* __restrict__ h0) {
    __shared__ float w[FI * FH];  // 32 KB
    int t = threadIdx.x;
    for (int i = t; i < FI * FH; i += 256) w[i] = W1[i];
    __syncthreads();
    int wave = t >> 6, lane = t & 63;
    int row = blockIdx.x * 4 + wave;  // grid = NN/4 = 25000 exactly
    float xlo = x[row * FI + lane];
    float xhi = x[row * FI + 64 + lane];
    float acc = 0.f;
#pragma unroll
    for (int c = 0; c < 64; ++c) {
        float xv = __shfl(xlo, c, 64);
        acc = fmaf(xv, w[c * FH + lane], acc);
    }
#pragma unroll
    for (int c = 0; c < 64; ++c) {
        float xv = __shfl(xhi, c, 64);
        acc = fmaf(xv, w[(64 + c) * FH + lane], acc);
    }
    h0[row * FH + lane] = acc;
}

// ---------------- agg1: gather + self + bias + relu + dropout --------------
// wave per node d, lane = feature. h1[d,f] = drop(relu(inv_d*(sum + h0[d,f]*inv_d) + b1))
__global__ __launch_bounds__(256) void k_agg1(const int* __restrict__ offs,
                                              const int* __restrict__ cnt,
                                              const int* __restrict__ csr_s,
                                              const float* __restrict__ csr_w,
                                              const float* __restrict__ inv,
                                              const float* __restrict__ h0,
                                              const float* __restrict__ b1,
                                              float* __restrict__ h1) {
    int lane = threadIdx.x & 63;
    int d = (blockIdx.x * blockDim.x + threadIdx.x) >> 6;  // exactly NN waves
    if (d >= NN) return;
    int start = offs[d], deg = cnt[d];
    float acc = 0.f;
    for (int base = 0; base < deg; base += 64) {
        int rem = deg - base; if (rem > 64) rem = 64;
        int s_l = 0; float w_l = 0.f;
        if (lane < rem) {
            s_l = csr_s[start + base + lane];
            w_l = csr_w[start + base + lane];
        }
        for (int k = 0; k < rem; ++k) {
            int s = __shfl(s_l, k, 64);
            float w = __shfl(w_l, k, 64);
            acc = fmaf(h0[s * FH + lane], w, acc);
        }
    }
    float invd = inv[d];
    float val = (acc + h0[d * FH + lane] * invd) * invd + b1[lane];
    val = fmaxf(val, 0.f);
    int i = d * FH + lane;
    unsigned o0, o1;
    threefry_0_42(0u, (unsigned)i, o0, o1);
    unsigned wbits = o0 ^ o1;            // partitionable f32 path: XOR fold
    h1[i] = (wbits >> 31) ? 0.f : val * 2.f;
}

// ---------------- GEMM2: h2[N,40] = h1[N,64] @ W2[64,40] -------------------
#define W2PAD (FH * FO + 64)
__global__ __launch_bounds__(256) void k_gemm2(const float* __restrict__ h,
                                               const float* __restrict__ W2,
                                               float* __restrict__ h2) {
    __shared__ float w[W2PAD];
    int t = threadIdx.x;
    for (int i = t; i < FH * FO; i += 256) w[i] = W2[i];
    for (int i = FH * FO + t; i < W2PAD; i += 256) w[i] = 0.f;
    __syncthreads();
    int wave = t >> 6, lane = t & 63;
    int row = blockIdx.x * 4 + wave;  // grid = 25000 exactly
    float hv = h[row * FH + lane];
    float acc = 0.f;
#pragma unroll
    for (int c = 0; c < FH; ++c) {
        float xv = __shfl(hv, c, 64);
        acc = fmaf(xv, w[c * FO + lane], acc);  // lanes >=40 read pad, discarded
    }
    if (lane < FO) h2[row * FO + lane] = acc;
}

// ---------------- agg2: gather + self + b2 -> out --------------------------
__global__ __launch_bounds__(256) void k_agg2(const int* __restrict__ offs,
                                              const int* __restrict__ cnt,
                                              const int* __restrict__ csr_s,
                                              const float* __restrict__ csr_w,
                                              const float* __restrict__ inv,
                                              const float* __restrict__ h2,
                                              const float* __restrict__ b2,
                                              float* __restrict__ out) {
    int lane = threadIdx.x & 63;
    int d = (blockIdx.x * blockDim.x + threadIdx.x) >> 6;
    if (d >= NN) return;
    int start = offs[d], deg = cnt[d];
    float acc = 0.f;
    for (int base = 0; base < deg; base += 64) {
        int rem = deg - base; if (rem > 64) rem = 64;
        int s_l = 0; float w_l = 0.f;
        if (lane < rem) {
            s_l = csr_s[start + base + lane];
            w_l = csr_w[start + base + lane];
        }
        for (int k = 0; k < rem; ++k) {
            int s = __shfl(s_l, k, 64);
            float w = __shfl(w_l, k, 64);
            float v = (lane < FO) ? h2[s * FO + lane] : 0.f;
            acc = fmaf(v, w, acc);
        }
    }
    if (lane < FO) {
        float invd = inv[d];
        out[d * FO + lane] = (acc + h2[d * FO + lane] * invd) * invd + b2[lane];
    }
}

extern "C" void kernel_launch(void* const* d_in, const int* in_sizes, int n_in,
                              void* d_out, int out_size, void* d_ws, size_t ws_size,
                              hipStream_t stream) {
    const float* x  = (const float*)d_in[0];
    const int*   ei = (const int*)d_in[1];   // int32 [2, NE]: src = ei[e], dst = ei[NE+e]
    const float* W1 = (const float*)d_in[2];
    const float* b1 = (const float*)d_in[3];
    const float* W2 = (const float*)d_in[4];
    const float* b2 = (const float*)d_in[5];
    float* out = (float*)d_out;

    char* ws = (char*)d_ws;
    int*   cnt    = (int*)ws;                              // 0.4 MB
    int*   offs   = (int*)(ws + (size_t)( 1 << 20));       // 0.4 MB
    int*   cursor = (int*)(ws + (size_t)( 2 << 20));       // 0.4 MB
    int*   bsum   = (int*)(ws + (size_t)( 3 << 20));       // 1.6 KB
    float* inv    = (float*)(ws + (size_t)( 4 << 20));     // 0.4 MB
    int*   csr_s  = (int*)(ws + (size_t)( 5 << 20));       // 6.4 MB
    float* csr_w  = (float*)(ws + (size_t)(12 << 20));     // 6.4 MB
    float* h0     = (float*)(ws + (size_t)(19 << 20));     // 25.6 MB
    float* h1     = (float*)(ws + (size_t)(45 << 20));     // 25.6 MB
    float* h2     = h0;                                    // reuse after agg1

    hipMemsetAsync(cnt, 0, NN * sizeof(int), stream);

    k_count<<<1024, 256, 0, stream>>>(ei, cnt);
    k_scanA<<<NB, 256, 0, stream>>>(cnt, offs, bsum);
    k_scanB<<<1, 512, 0, stream>>>(bsum);
    k_scanC<<<NB, 256, 0, stream>>>(offs, bsum, cursor);
    k_inv<<<NB, 256, 0, stream>>>(cnt, inv);
    k_fill<<<1024, 256, 0, stream>>>(ei, inv, cursor, csr_s, csr_w);

    k_gemm1<<<NN / 4, 256, 0, stream>>>(x, W1, h0);
    k_agg1<<<NN / 4, 256, 0, stream>>>(offs, cnt, csr_s, csr_w, inv, h0, b1, h1);

    k_gemm2<<<NN / 4, 256, 0, stream>>>(h1, W2, h2);
    k_agg2<<<NN / 4, 256, 0, stream>>>(offs, cnt, csr_s, csr_w, inv, h2, b2, out);
}

// Round 7
// 444.638 us; speedup vs baseline: 2.2964x; 1.6000x over previous
//
#include <hip/hip_runtime.h>

#define NN 100000
#define NE 1600000
#define FI 128
#define FH 64
#define FO 40
#define NH (NN * FH)            // 6,400,000 mask elements
#define NB ((NN + 255) / 256)   // 391 scan blocks

// ---------------- Threefry-2x32, key = (0, 42) -----------------------------
__device__ __forceinline__ unsigned rotl32(unsigned v, unsigned r) {
    return (v << r) | (v >> (32u - r));
}

__device__ __forceinline__ void threefry_0_42(unsigned x0, unsigned x1,
                                              unsigned& o0, unsigned& o1) {
    const unsigned k0 = 0u, k1 = 42u;
    const unsigned k2 = 0x1BD11BDAu ^ k0 ^ k1;
    x0 += k0; x1 += k1;
#define TFR(r) { x0 += x1; x1 = rotl32(x1, r); x1 ^= x0; }
    TFR(13) TFR(15) TFR(26) TFR(6)   x0 += k1; x1 += k2 + 1u;
    TFR(17) TFR(29) TFR(16) TFR(24)  x0 += k2; x1 += k0 + 2u;
    TFR(13) TFR(15) TFR(26) TFR(6)   x0 += k0; x1 += k1 + 3u;
    TFR(17) TFR(29) TFR(16) TFR(24)  x0 += k1; x1 += k2 + 4u;
    TFR(13) TFR(15) TFR(26) TFR(6)   x0 += k2; x1 += k0 + 5u;
#undef TFR
    o0 = x0; o1 = x1;
}

// ---------------- degree count (int) ---------------------------------------
__global__ __launch_bounds__(256) void k_count(const int* __restrict__ ei,
                                               int* __restrict__ cnt) {
    int i = blockIdx.x * blockDim.x + threadIdx.x;
    int stride = gridDim.x * blockDim.x;
    for (; i < NE; i += stride) atomicAdd(&cnt[ei[NE + i]], 1);
}

// ---------------- 3-kernel exclusive scan ----------------------------------
__global__ __launch_bounds__(256) void k_scanA(const int* __restrict__ cnt,
                                               int* __restrict__ offs,
                                               int* __restrict__ bsum) {
    __shared__ int sh[256];
    int t = threadIdx.x, g = blockIdx.x * 256 + t;
    int v = (g < NN) ? cnt[g] : 0;
    sh[t] = v;
    __syncthreads();
    for (int off = 1; off < 256; off <<= 1) {
        int u = (t >= off) ? sh[t - off] : 0;
        __syncthreads();
        sh[t] += u;
        __syncthreads();
    }
    if (g < NN) offs[g] = sh[t] - v;               // exclusive within block
    if (t == 255) bsum[blockIdx.x] = sh[255];      // block total
}

__global__ __launch_bounds__(512) void k_scanB(int* __restrict__ bsum) {
    __shared__ int sh[512];
    int t = threadIdx.x;
    int v = (t < NB) ? bsum[t] : 0;
    sh[t] = v;
    __syncthreads();
    for (int off = 1; off < 512; off <<= 1) {
        int u = (t >= off) ? sh[t - off] : 0;
        __syncthreads();
        sh[t] += u;
        __syncthreads();
    }
    if (t < NB) bsum[t] = sh[t] - v;               // exclusive block offsets
}

__global__ __launch_bounds__(256) void k_scanC(int* __restrict__ offs,
                                               const int* __restrict__ bsum,
                                               int* __restrict__ cursor) {
    int g = blockIdx.x * 256 + threadIdx.x;
    if (g < NN) {
        int o = offs[g] + bsum[blockIdx.x];
        offs[g] = o;
        cursor[g] = o;
    }
}

// ---------------- inv = rsqrt(cnt + 1) -------------------------------------
__global__ __launch_bounds__(256) void k_inv(const int* __restrict__ cnt,
                                             float* __restrict__ inv) {
    int i = blockIdx.x * blockDim.x + threadIdx.x;
    if (i < NN) inv[i] = rsqrtf((float)cnt[i] + 1.0f);
}

// ---------------- CSR fill: bucket src id + src weight by dst --------------
__global__ __launch_bounds__(256) void k_fill(const int* __restrict__ ei,
                                              const float* __restrict__ inv,
                                              int* __restrict__ cursor,
                                              int* __restrict__ csr_s,
                                              float* __restrict__ csr_w) {
    int i = blockIdx.x * blockDim.x + threadIdx.x;
    int stride = gridDim.x * blockDim.x;
    for (; i < NE; i += stride) {
        int s = ei[i];
        int d = ei[NE + i];
        int pos = atomicAdd(&cursor[d], 1);
        csr_s[pos] = s;
        csr_w[pos] = inv[s];
    }
}

// ---------------- GEMM1: h0[N,64] = x[N,128] @ W1[128,64] ------------------
// 8 rows per wave; x addressed wave-uniformly -> s_load broadcast; W in LDS.
__global__ __launch_bounds__(256) void k_gemm1(const float* __restrict__ x,
                                               const float* __restrict__ W1,
                                               float* __restrict__ h0) {
    __shared__ float w[FI * FH];  // 32 KB
    int t = threadIdx.x;
    for (int i = t; i < FI * FH; i += 256) w[i] = W1[i];
    __syncthreads();
    int lane = t & 63;
    int wv = __builtin_amdgcn_readfirstlane(t >> 6);
    int row0 = blockIdx.x * 32 + wv * 8;   // grid = NN/32 = 3125 exactly
    const float* xp = x + (size_t)row0 * FI;
    float acc[8] = {0.f, 0.f, 0.f, 0.f, 0.f, 0.f, 0.f, 0.f};
#pragma unroll 4
    for (int k = 0; k < FI; ++k) {
        float wk = w[k * FH + lane];
#pragma unroll
        for (int r = 0; r < 8; ++r)
            acc[r] = fmaf(xp[r * FI + k], wk, acc[r]);  // uniform x -> SGPR
    }
#pragma unroll
    for (int r = 0; r < 8; ++r)
        h0[(size_t)(row0 + r) * FH + lane] = acc[r];
}

// ---------------- agg1: gather + self + bias + relu + dropout --------------
// wave per node d; csr reads are wave-uniform -> s_load; gather is coalesced.
__global__ __launch_bounds__(256) void k_agg1(const int* __restrict__ offs,
                                              const int* __restrict__ cnt,
                                              const int* __restrict__ csr_s,
                                              const float* __restrict__ csr_w,
                                              const float* __restrict__ inv,
                                              const float* __restrict__ h0,
                                              const float* __restrict__ b1,
                                              float* __restrict__ h1) {
    int lane = threadIdx.x & 63;
    int d = __builtin_amdgcn_readfirstlane((int)(blockIdx.x * 4 + (threadIdx.x >> 6)));
    if (d >= NN) return;
    int start = offs[d], deg = cnt[d];
    float acc = 0.f;
    int k = 0;
    for (; k + 2 <= deg; k += 2) {
        int   s0 = csr_s[start + k],     s1 = csr_s[start + k + 1];
        float w0 = csr_w[start + k],     w1 = csr_w[start + k + 1];
        float v0 = h0[(size_t)s0 * FH + lane];
        float v1 = h0[(size_t)s1 * FH + lane];
        acc = fmaf(v0, w0, acc);
        acc = fmaf(v1, w1, acc);
    }
    if (k < deg) {
        int s = csr_s[start + k];
        acc = fmaf(h0[(size_t)s * FH + lane], csr_w[start + k], acc);
    }
    float invd = inv[d];
    float val = (acc + h0[(size_t)d * FH + lane] * invd) * invd + b1[lane];
    val = fmaxf(val, 0.f);
    int i = d * FH + lane;
    unsigned o0, o1;
    threefry_0_42(0u, (unsigned)i, o0, o1);
    unsigned wbits = o0 ^ o1;            // partitionable f32 path: XOR fold
    h1[i] = (wbits >> 31) ? 0.f : val * 2.f;
}

// ---------------- GEMM2: h2[N,40] = h1[N,64] @ W2[64,40] -------------------
__global__ __launch_bounds__(256) void k_gemm2(const float* __restrict__ h,
                                               const float* __restrict__ W2,
                                               float* __restrict__ h2) {
    __shared__ float w[FH * FO];  // 10.2 KB
    int t = threadIdx.x;
    for (int i = t; i < FH * FO; i += 256) w[i] = W2[i];
    __syncthreads();
    int lane = t & 63;
    int wv = __builtin_amdgcn_readfirstlane(t >> 6);
    int row0 = blockIdx.x * 32 + wv * 8;   // grid = 3125 exactly
    const float* hp = h + (size_t)row0 * FH;
    float acc[8] = {0.f, 0.f, 0.f, 0.f, 0.f, 0.f, 0.f, 0.f};
    int c = (lane < FO) ? lane : 0;        // lanes >=40 compute col 0, discarded
#pragma unroll 4
    for (int k = 0; k < FH; ++k) {
        float wk = w[k * FO + c];
#pragma unroll
        for (int r = 0; r < 8; ++r)
            acc[r] = fmaf(hp[r * FH + k], wk, acc[r]);  // uniform h -> SGPR
    }
    if (lane < FO) {
#pragma unroll
        for (int r = 0; r < 8; ++r)
            h2[(size_t)(row0 + r) * FO + lane] = acc[r];
    }
}

// ---------------- agg2: gather + self + b2 -> out --------------------------
__global__ __launch_bounds__(256) void k_agg2(const int* __restrict__ offs,
                                              const int* __restrict__ cnt,
                                              const int* __restrict__ csr_s,
                                              const float* __restrict__ csr_w,
                                              const float* __restrict__ inv,
                                              const float* __restrict__ h2,
                                              const float* __restrict__ b2,
                                              float* __restrict__ out) {
    int lane = threadIdx.x & 63;
    int d = __builtin_amdgcn_readfirstlane((int)(blockIdx.x * 4 + (threadIdx.x >> 6)));
    if (d >= NN) return;
    int start = offs[d], deg = cnt[d];
    int c = (lane < FO) ? lane : 0;
    float acc = 0.f;
    int k = 0;
    for (; k + 2 <= deg; k += 2) {
        int   s0 = csr_s[start + k],     s1 = csr_s[start + k + 1];
        float w0 = csr_w[start + k],     w1 = csr_w[start + k + 1];
        float v0 = h2[(size_t)s0 * FO + c];
        float v1 = h2[(size_t)s1 * FO + c];
        acc = fmaf(v0, w0, acc);
        acc = fmaf(v1, w1, acc);
    }
    if (k < deg) {
        int s = csr_s[start + k];
        acc = fmaf(h2[(size_t)s * FO + c], csr_w[start + k], acc);
    }
    if (lane < FO) {
        float invd = inv[d];
        out[(size_t)d * FO + lane] = (acc + h2[(size_t)d * FO + lane] * invd) * invd + b2[lane];
    }
}

extern "C" void kernel_launch(void* const* d_in, const int* in_sizes, int n_in,
                              void* d_out, int out_size, void* d_ws, size_t ws_size,
                              hipStream_t stream) {
    const float* x  = (const float*)d_in[0];
    const int*   ei = (const int*)d_in[1];   // int32 [2, NE]: src = ei[e], dst = ei[NE+e]
    const float* W1 = (const float*)d_in[2];
    const float* b1 = (const float*)d_in[3];
    const float* W2 = (const float*)d_in[4];
    const float* b2 = (const float*)d_in[5];
    float* out = (float*)d_out;

    char* ws = (char*)d_ws;
    int*   cnt    = (int*)ws;                              // 0.4 MB
    int*   offs   = (int*)(ws + (size_t)( 1 << 20));       // 0.4 MB
    int*   cursor = (int*)(ws + (size_t)( 2 << 20));       // 0.4 MB
    int*   bsum   = (int*)(ws + (size_t)( 3 << 20));       // 1.6 KB
    float* inv    = (float*)(ws + (size_t)( 4 << 20));     // 0.4 MB
    int*   csr_s  = (int*)(ws + (size_t)( 5 << 20));       // 6.4 MB
    float* csr_w  = (float*)(ws + (size_t)(12 << 20));     // 6.4 MB
    float* h0     = (float*)(ws + (size_t)(19 << 20));     // 25.6 MB
    float* h1     = (float*)(ws + (size_t)(45 << 20));     // 25.6 MB
    float* h2     = h0;                                    // reuse after agg1

    hipMemsetAsync(cnt, 0, NN * sizeof(int), stream);

    k_count<<<1024, 256, 0, stream>>>(ei, cnt);
    k_scanA<<<NB, 256, 0, stream>>>(cnt, offs, bsum);
    k_scanB<<<1, 512, 0, stream>>>(bsum);
    k_scanC<<<NB, 256, 0, stream>>>(offs, bsum, cursor);
    k_inv<<<NB, 256, 0, stream>>>(cnt, inv);
    k_fill<<<1024, 256, 0, stream>>>(ei, inv, cursor, csr_s, csr_w);

    k_gemm1<<<NN / 32, 256, 0, stream>>>(x, W1, h0);
    k_agg1<<<NN / 4, 256, 0, stream>>>(offs, cnt, csr_s, csr_w, inv, h0, b1, h1);

    k_gemm2<<<NN / 32, 256, 0, stream>>>(h1, W2, h2);
    k_agg2<<<NN / 4, 256, 0, stream>>>(offs, cnt, csr_s, csr_w, inv, h2, b2, out);
}

// Round 8
// 346.639 us; speedup vs baseline: 2.9456x; 1.2827x over previous
//
#include <hip/hip_runtime.h>

#define NN 100000
#define NE 1600000
#define FI 128
#define FH 64
#define FO 40
#define NB ((NN + 255) / 256)   // 391 scan blocks

// ---------------- Threefry-2x32, key = (0, 42) -----------------------------
__device__ __forceinline__ unsigned rotl32(unsigned v, unsigned r) {
    return (v << r) | (v >> (32u - r));
}

__device__ __forceinline__ void threefry_0_42(unsigned x0, unsigned x1,
                                              unsigned& o0, unsigned& o1) {
    const unsigned k0 = 0u, k1 = 42u;
    const unsigned k2 = 0x1BD11BDAu ^ k0 ^ k1;
    x0 += k0; x1 += k1;
#define TFR(r) { x0 += x1; x1 = rotl32(x1, r); x1 ^= x0; }
    TFR(13) TFR(15) TFR(26) TFR(6)   x0 += k1; x1 += k2 + 1u;
    TFR(17) TFR(29) TFR(16) TFR(24)  x0 += k2; x1 += k0 + 2u;
    TFR(13) TFR(15) TFR(26) TFR(6)   x0 += k0; x1 += k1 + 3u;
    TFR(17) TFR(29) TFR(16) TFR(24)  x0 += k1; x1 += k2 + 4u;
    TFR(13) TFR(15) TFR(26) TFR(6)   x0 += k2; x1 += k0 + 5u;
#undef TFR
    o0 = x0; o1 = x1;
}

// ---------------- degree count + per-edge rank -----------------------------
__global__ __launch_bounds__(256) void k_count(const int* __restrict__ ei,
                                               int* __restrict__ cnt,
                                               int* __restrict__ rank) {
    int i = blockIdx.x * blockDim.x + threadIdx.x;
    int stride = gridDim.x * blockDim.x;
    for (; i < NE; i += stride) {
        rank[i] = atomicAdd(&cnt[ei[NE + i]], 1);  // rank within dst, coalesced store
    }
}

// ---------------- 3-kernel exclusive scan ----------------------------------
__global__ __launch_bounds__(256) void k_scanA(const int* __restrict__ cnt,
                                               int* __restrict__ offs,
                                               int* __restrict__ bsum) {
    __shared__ int sh[256];
    int t = threadIdx.x, g = blockIdx.x * 256 + t;
    int v = (g < NN) ? cnt[g] : 0;
    sh[t] = v;
    __syncthreads();
    for (int off = 1; off < 256; off <<= 1) {
        int u = (t >= off) ? sh[t - off] : 0;
        __syncthreads();
        sh[t] += u;
        __syncthreads();
    }
    if (g < NN) offs[g] = sh[t] - v;               // exclusive within block
    if (t == 255) bsum[blockIdx.x] = sh[255];      // block total
}

__global__ __launch_bounds__(512) void k_scanB(int* __restrict__ bsum) {
    __shared__ int sh[512];
    int t = threadIdx.x;
    int v = (t < NB) ? bsum[t] : 0;
    sh[t] = v;
    __syncthreads();
    for (int off = 1; off < 512; off <<= 1) {
        int u = (t >= off) ? sh[t - off] : 0;
        __syncthreads();
        sh[t] += u;
        __syncthreads();
    }
    if (t < NB) bsum[t] = sh[t] - v;               // exclusive block offsets
}

__global__ __launch_bounds__(256) void k_scanC(int* __restrict__ offs,
                                               const int* __restrict__ bsum) {
    int g = blockIdx.x * 256 + threadIdx.x;
    if (g < NN) offs[g] += bsum[blockIdx.x];
}

// ---------------- inv = rsqrt(cnt + 1) -------------------------------------
__global__ __launch_bounds__(256) void k_inv(const int* __restrict__ cnt,
                                             float* __restrict__ inv) {
    int i = blockIdx.x * blockDim.x + threadIdx.x;
    if (i < NN) inv[i] = rsqrtf((float)cnt[i] + 1.0f);
}

// ---------------- CSR fill: packed (src, w) single 8B store, no atomics ----
__global__ __launch_bounds__(256) void k_fill(const int* __restrict__ ei,
                                              const int* __restrict__ rank,
                                              const int* __restrict__ offs,
                                              const float* __restrict__ inv,
                                              int2* __restrict__ csr) {
    int i = blockIdx.x * blockDim.x + threadIdx.x;
    int stride = gridDim.x * blockDim.x;
    for (; i < NE; i += stride) {
        int s = ei[i];
        int d = ei[NE + i];
        int pos = offs[d] + rank[i];
        csr[pos] = make_int2(s, __float_as_int(inv[s]));
    }
}

// ---------------- GEMM1: h0[N,64] = x[N,128] @ W1[128,64] ------------------
// 8 rows per wave; x addressed wave-uniformly -> s_load broadcast; W in LDS.
__global__ __launch_bounds__(256) void k_gemm1(const float* __restrict__ x,
                                               const float* __restrict__ W1,
                                               float* __restrict__ h0) {
    __shared__ float w[FI * FH];  // 32 KB
    int t = threadIdx.x;
    for (int i = t; i < FI * FH; i += 256) w[i] = W1[i];
    __syncthreads();
    int lane = t & 63;
    int wv = __builtin_amdgcn_readfirstlane(t >> 6);
    int row0 = blockIdx.x * 32 + wv * 8;   // grid = NN/32 = 3125 exactly
    const float* xp = x + (size_t)row0 * FI;
    float acc[8] = {0.f, 0.f, 0.f, 0.f, 0.f, 0.f, 0.f, 0.f};
#pragma unroll 4
    for (int k = 0; k < FI; ++k) {
        float wk = w[k * FH + lane];
#pragma unroll
        for (int r = 0; r < 8; ++r)
            acc[r] = fmaf(xp[r * FI + k], wk, acc[r]);  // uniform x -> SGPR
    }
#pragma unroll
    for (int r = 0; r < 8; ++r)
        h0[(size_t)(row0 + r) * FH + lane] = acc[r];
}

// ---------------- agg1: gather + self + bias + relu + dropout --------------
__global__ __launch_bounds__(256) void k_agg1(const int* __restrict__ offs,
                                              const int* __restrict__ cnt,
                                              const int2* __restrict__ csr,
                                              const float* __restrict__ inv,
                                              const float* __restrict__ h0,
                                              const float* __restrict__ b1,
                                              float* __restrict__ h1) {
    int lane = threadIdx.x & 63;
    int d = __builtin_amdgcn_readfirstlane((int)(blockIdx.x * 4 + (threadIdx.x >> 6)));
    if (d >= NN) return;
    int start = offs[d], deg = cnt[d];
    float acc = 0.f;
    int k = 0;
    for (; k + 2 <= deg; k += 2) {
        int2 sw0 = csr[start + k];
        int2 sw1 = csr[start + k + 1];
        float v0 = h0[(size_t)sw0.x * FH + lane];
        float v1 = h0[(size_t)sw1.x * FH + lane];
        acc = fmaf(v0, __int_as_float(sw0.y), acc);
        acc = fmaf(v1, __int_as_float(sw1.y), acc);
    }
    if (k < deg) {
        int2 sw = csr[start + k];
        acc = fmaf(h0[(size_t)sw.x * FH + lane], __int_as_float(sw.y), acc);
    }
    float invd = inv[d];
    float val = (acc + h0[(size_t)d * FH + lane] * invd) * invd + b1[lane];
    val = fmaxf(val, 0.f);
    int i = d * FH + lane;
    unsigned o0, o1;
    threefry_0_42(0u, (unsigned)i, o0, o1);
    unsigned wbits = o0 ^ o1;            // partitionable f32 path: XOR fold
    h1[i] = (wbits >> 31) ? 0.f : val * 2.f;
}

// ---------------- GEMM2: h2[N,40] = h1[N,64] @ W2[64,40] -------------------
__global__ __launch_bounds__(256) void k_gemm2(const float* __restrict__ h,
                                               const float* __restrict__ W2,
                                               float* __restrict__ h2) {
    __shared__ float w[FH * FO];  // 10.2 KB
    int t = threadIdx.x;
    for (int i = t; i < FH * FO; i += 256) w[i] = W2[i];
    __syncthreads();
    int lane = t & 63;
    int wv = __builtin_amdgcn_readfirstlane(t >> 6);
    int row0 = blockIdx.x * 32 + wv * 8;   // grid = 3125 exactly
    const float* hp = h + (size_t)row0 * FH;
    float acc[8] = {0.f, 0.f, 0.f, 0.f, 0.f, 0.f, 0.f, 0.f};
    int c = (lane < FO) ? lane : 0;        // lanes >=40 compute col 0, discarded
#pragma unroll 4
    for (int k = 0; k < FH; ++k) {
        float wk = w[k * FO + c];
#pragma unroll
        for (int r = 0; r < 8; ++r)
            acc[r] = fmaf(hp[r * FH + k], wk, acc[r]);  // uniform h -> SGPR
    }
    if (lane < FO) {
#pragma unroll
        for (int r = 0; r < 8; ++r)
            h2[(size_t)(row0 + r) * FO + lane] = acc[r];
    }
}

// ---------------- agg2: gather + self + b2 -> out --------------------------
__global__ __launch_bounds__(256) void k_agg2(const int* __restrict__ offs,
                                              const int* __restrict__ cnt,
                                              const int2* __restrict__ csr,
                                              const float* __restrict__ inv,
                                              const float* __restrict__ h2,
                                              const float* __restrict__ b2,
                                              float* __restrict__ out) {
    int lane = threadIdx.x & 63;
    int d = __builtin_amdgcn_readfirstlane((int)(blockIdx.x * 4 + (threadIdx.x >> 6)));
    if (d >= NN) return;
    int start = offs[d], deg = cnt[d];
    int c = (lane < FO) ? lane : 0;
    float acc = 0.f;
    int k = 0;
    for (; k + 2 <= deg; k += 2) {
        int2 sw0 = csr[start + k];
        int2 sw1 = csr[start + k + 1];
        float v0 = h2[(size_t)sw0.x * FO + c];
        float v1 = h2[(size_t)sw1.x * FO + c];
        acc = fmaf(v0, __int_as_float(sw0.y), acc);
        acc = fmaf(v1, __int_as_float(sw1.y), acc);
    }
    if (k < deg) {
        int2 sw = csr[start + k];
        acc = fmaf(h2[(size_t)sw.x * FO + c], __int_as_float(sw.y), acc);
    }
    if (lane < FO) {
        float invd = inv[d];
        out[(size_t)d * FO + lane] = (acc + h2[(size_t)d * FO + lane] * invd) * invd + b2[lane];
    }
}

extern "C" void kernel_launch(void* const* d_in, const int* in_sizes, int n_in,
                              void* d_out, int out_size, void* d_ws, size_t ws_size,
                              hipStream_t stream) {
    const float* x  = (const float*)d_in[0];
    const int*   ei = (const int*)d_in[1];   // int32 [2, NE]: src = ei[e], dst = ei[NE+e]
    const float* W1 = (const float*)d_in[2];
    const float* b1 = (const float*)d_in[3];
    const float* W2 = (const float*)d_in[4];
    const float* b2 = (const float*)d_in[5];
    float* out = (float*)d_out;

    char* ws = (char*)d_ws;
    int*   cnt   = (int*)ws;                              // 0.4 MB
    int*   offs  = (int*)(ws + (size_t)( 1 << 20));       // 0.4 MB
    int*   bsum  = (int*)(ws + (size_t)( 2 << 20));       // 1.6 KB
    float* inv   = (float*)(ws + (size_t)( 3 << 20));     // 0.4 MB
    int*   rank  = (int*)(ws + (size_t)( 4 << 20));       // 6.4 MB
    int2*  csr   = (int2*)(ws + (size_t)(11 << 20));      // 12.8 MB
    float* h0    = (float*)(ws + (size_t)(24 << 20));     // 25.6 MB
    float* h1    = (float*)(ws + (size_t)(50 << 20));     // 25.6 MB
    float* h2    = h0;                                    // reuse after agg1

    hipMemsetAsync(cnt, 0, NN * sizeof(int), stream);

    k_count<<<2048, 256, 0, stream>>>(ei, cnt, rank);
    k_scanA<<<NB, 256, 0, stream>>>(cnt, offs, bsum);
    k_scanB<<<1, 512, 0, stream>>>(bsum);
    k_scanC<<<NB, 256, 0, stream>>>(offs, bsum);
    k_inv<<<NB, 256, 0, stream>>>(cnt, inv);
    k_fill<<<2048, 256, 0, stream>>>(ei, rank, offs, inv, csr);

    k_gemm1<<<NN / 32, 256, 0, stream>>>(x, W1, h0);
    k_agg1<<<NN / 4, 256, 0, stream>>>(offs, cnt, csr, inv, h0, b1, h1);

    k_gemm2<<<NN / 32, 256, 0, stream>>>(h1, W2, h2);
    k_agg2<<<NN / 4, 256, 0, stream>>>(offs, cnt, csr, inv, h2, b2, out);
}

// Round 9
// 304.151 us; speedup vs baseline: 3.3571x; 1.1397x over previous
//
#include <hip/hip_runtime.h>

#define NN 100000
#define NE 1600000
#define FI 128
#define FH 64
#define FO 40
#define NB ((NN + 255) / 256)   // 391 scan blocks

// ---------------- Threefry-2x32, key = (0, 42) -----------------------------
__device__ __forceinline__ unsigned rotl32(unsigned v, unsigned r) {
    return (v << r) | (v >> (32u - r));
}

__device__ __forceinline__ void threefry_0_42(unsigned x0, unsigned x1,
                                              unsigned& o0, unsigned& o1) {
    const unsigned k0 = 0u, k1 = 42u;
    const unsigned k2 = 0x1BD11BDAu ^ k0 ^ k1;
    x0 += k0; x1 += k1;
#define TFR(r) { x0 += x1; x1 = rotl32(x1, r); x1 ^= x0; }
    TFR(13) TFR(15) TFR(26) TFR(6)   x0 += k1; x1 += k2 + 1u;
    TFR(17) TFR(29) TFR(16) TFR(24)  x0 += k2; x1 += k0 + 2u;
    TFR(13) TFR(15) TFR(26) TFR(6)   x0 += k0; x1 += k1 + 3u;
    TFR(17) TFR(29) TFR(16) TFR(24)  x0 += k1; x1 += k2 + 4u;
    TFR(13) TFR(15) TFR(26) TFR(6)   x0 += k2; x1 += k0 + 5u;
#undef TFR
    o0 = x0; o1 = x1;
}

// ---------------- degree count + per-edge rank -----------------------------
__global__ __launch_bounds__(256) void k_count(const int* __restrict__ ei,
                                               int* __restrict__ cnt,
                                               int* __restrict__ rank) {
    int i = blockIdx.x * blockDim.x + threadIdx.x;
    int stride = gridDim.x * blockDim.x;
    for (; i < NE; i += stride) {
        rank[i] = atomicAdd(&cnt[ei[NE + i]], 1);  // rank within dst, coalesced store
    }
}

// ---------------- 3-kernel exclusive scan ----------------------------------
__global__ __launch_bounds__(256) void k_scanA(const int* __restrict__ cnt,
                                               int* __restrict__ offs,
                                               int* __restrict__ bsum) {
    __shared__ int sh[256];
    int t = threadIdx.x, g = blockIdx.x * 256 + t;
    int v = (g < NN) ? cnt[g] : 0;
    sh[t] = v;
    __syncthreads();
    for (int off = 1; off < 256; off <<= 1) {
        int u = (t >= off) ? sh[t - off] : 0;
        __syncthreads();
        sh[t] += u;
        __syncthreads();
    }
    if (g < NN) offs[g] = sh[t] - v;               // exclusive within block
    if (t == 255) bsum[blockIdx.x] = sh[255];      // block total
}

__global__ __launch_bounds__(512) void k_scanB(int* __restrict__ bsum) {
    __shared__ int sh[512];
    int t = threadIdx.x;
    int v = (t < NB) ? bsum[t] : 0;
    sh[t] = v;
    __syncthreads();
    for (int off = 1; off < 512; off <<= 1) {
        int u = (t >= off) ? sh[t - off] : 0;
        __syncthreads();
        sh[t] += u;
        __syncthreads();
    }
    if (t < NB) bsum[t] = sh[t] - v;               // exclusive block offsets
}

__global__ __launch_bounds__(256) void k_scanC(int* __restrict__ offs,
                                               const int* __restrict__ bsum) {
    int g = blockIdx.x * 256 + threadIdx.x;
    if (g < NN) offs[g] += bsum[blockIdx.x];
}

// ---------------- inv = rsqrt(cnt + 1) -------------------------------------
__global__ __launch_bounds__(256) void k_inv(const int* __restrict__ cnt,
                                             float* __restrict__ inv) {
    int i = blockIdx.x * blockDim.x + threadIdx.x;
    if (i < NN) inv[i] = rsqrtf((float)cnt[i] + 1.0f);
}

// ---------------- CSR fill: packed (src, w) single 8B store, no atomics ----
__global__ __launch_bounds__(256) void k_fill(const int* __restrict__ ei,
                                              const int* __restrict__ rank,
                                              const int* __restrict__ offs,
                                              const float* __restrict__ inv,
                                              int2* __restrict__ csr) {
    int i = blockIdx.x * blockDim.x + threadIdx.x;
    int stride = gridDim.x * blockDim.x;
    for (; i < NE; i += stride) {
        int s = ei[i];
        int d = ei[NE + i];
        int pos = offs[d] + rank[i];
        csr[pos] = make_int2(s, __float_as_int(inv[s]));
    }
}

// ---------------- GEMM1: h0[N,64] = x[N,128] @ W1[128,64] ------------------
// LDS-tiled, 4x4 register tile per thread, k unrolled x4, b128 LDS reads.
// W1 staged in two 64-row halves to keep LDS at 50 KB (3 blocks/CU).
#define XS_STRIDE 132   // 128 + 4: keeps b128 16B-aligned; rows on distinct banks
__global__ __launch_bounds__(256) void k_gemm1(const float* __restrict__ x,
                                               const float* __restrict__ W1,
                                               float* __restrict__ h0) {
    __shared__ float xs[64 * XS_STRIDE];   // 33.8 KB
    __shared__ float ws[64 * FH];          // 16 KB (one K-half of W1)
    int t = threadIdx.x;
    int row0 = blockIdx.x * 64;
    // stage x tile: 64 rows x 128 cols, coalesced float4
    {
        int r = t >> 5;              // 0..7
        int c4 = (t & 31) * 4;       // 0..124
#pragma unroll
        for (int p = 0; p < 8; ++p) {
            int row = row0 + r + p * 8;
            float4 v = make_float4(0.f, 0.f, 0.f, 0.f);
            if (row < NN) v = *(const float4*)&x[(size_t)row * FI + c4];
            *(float4*)&xs[(r + p * 8) * XS_STRIDE + c4] = v;
        }
    }
    float acc[4][4] = {{0.f}};
    int tx4 = (t & 15) * 4;
    int ty4 = (t >> 4) * 4;
#pragma unroll
    for (int half = 0; half < 2; ++half) {
        __syncthreads();   // half 0: after x staging; half 1: protect ws rewrite
        {
            const float4* Wv = (const float4*)(W1 + half * 64 * FH);
            float4* wv = (float4*)ws;
            for (int i = t; i < 64 * FH / 4; i += 256) wv[i] = Wv[i];
        }
        __syncthreads();
#pragma unroll 2
        for (int k = 0; k < 64; k += 4) {
            float4 a0 = *(const float4*)&xs[(ty4 + 0) * XS_STRIDE + half * 64 + k];
            float4 a1 = *(const float4*)&xs[(ty4 + 1) * XS_STRIDE + half * 64 + k];
            float4 a2 = *(const float4*)&xs[(ty4 + 2) * XS_STRIDE + half * 64 + k];
            float4 a3 = *(const float4*)&xs[(ty4 + 3) * XS_STRIDE + half * 64 + k];
            float4 b0 = *(const float4*)&ws[(k + 0) * FH + tx4];
            float4 b1 = *(const float4*)&ws[(k + 1) * FH + tx4];
            float4 b2 = *(const float4*)&ws[(k + 2) * FH + tx4];
            float4 b3 = *(const float4*)&ws[(k + 3) * FH + tx4];
#define KK1(AE, BV) \
            acc[0][0] = fmaf(a0.AE, BV.x, acc[0][0]); \
            acc[0][1] = fmaf(a0.AE, BV.y, acc[0][1]); \
            acc[0][2] = fmaf(a0.AE, BV.z, acc[0][2]); \
            acc[0][3] = fmaf(a0.AE, BV.w, acc[0][3]); \
            acc[1][0] = fmaf(a1.AE, BV.x, acc[1][0]); \
            acc[1][1] = fmaf(a1.AE, BV.y, acc[1][1]); \
            acc[1][2] = fmaf(a1.AE, BV.z, acc[1][2]); \
            acc[1][3] = fmaf(a1.AE, BV.w, acc[1][3]); \
            acc[2][0] = fmaf(a2.AE, BV.x, acc[2][0]); \
            acc[2][1] = fmaf(a2.AE, BV.y, acc[2][1]); \
            acc[2][2] = fmaf(a2.AE, BV.z, acc[2][2]); \
            acc[2][3] = fmaf(a2.AE, BV.w, acc[2][3]); \
            acc[3][0] = fmaf(a3.AE, BV.x, acc[3][0]); \
            acc[3][1] = fmaf(a3.AE, BV.y, acc[3][1]); \
            acc[3][2] = fmaf(a3.AE, BV.z, acc[3][2]); \
            acc[3][3] = fmaf(a3.AE, BV.w, acc[3][3]);
            KK1(x, b0) KK1(y, b1) KK1(z, b2) KK1(w, b3)
#undef KK1
        }
    }
#pragma unroll
    for (int i = 0; i < 4; ++i) {
        int row = row0 + ty4 + i;
        if (row < NN)
            *(float4*)&h0[(size_t)row * FH + tx4] =
                make_float4(acc[i][0], acc[i][1], acc[i][2], acc[i][3]);
    }
}

// ---------------- agg1: gather + self + bias + relu + dropout --------------
__global__ __launch_bounds__(256) void k_agg1(const int* __restrict__ offs,
                                              const int* __restrict__ cnt,
                                              const int2* __restrict__ csr,
                                              const float* __restrict__ inv,
                                              const float* __restrict__ h0,
                                              const float* __restrict__ b1,
                                              float* __restrict__ h1) {
    int lane = threadIdx.x & 63;
    int d = __builtin_amdgcn_readfirstlane((int)(blockIdx.x * 4 + (threadIdx.x >> 6)));
    if (d >= NN) return;
    int start = offs[d], deg = cnt[d];
    float acc = 0.f;
    int k = 0;
    for (; k + 2 <= deg; k += 2) {
        int2 sw0 = csr[start + k];
        int2 sw1 = csr[start + k + 1];
        float v0 = h0[(size_t)sw0.x * FH + lane];
        float v1 = h0[(size_t)sw1.x * FH + lane];
        acc = fmaf(v0, __int_as_float(sw0.y), acc);
        acc = fmaf(v1, __int_as_float(sw1.y), acc);
    }
    if (k < deg) {
        int2 sw = csr[start + k];
        acc = fmaf(h0[(size_t)sw.x * FH + lane], __int_as_float(sw.y), acc);
    }
    float invd = inv[d];
    float val = (acc + h0[(size_t)d * FH + lane] * invd) * invd + b1[lane];
    val = fmaxf(val, 0.f);
    int i = d * FH + lane;
    unsigned o0, o1;
    threefry_0_42(0u, (unsigned)i, o0, o1);
    unsigned wbits = o0 ^ o1;            // partitionable f32 path: XOR fold
    h1[i] = (wbits >> 31) ? 0.f : val * 2.f;
}

// ---------------- GEMM2: h2[N,40] = h1[N,64] @ W2[64,40] -------------------
#define HS_STRIDE 68    // 64 + 4: b128-aligned, rows on distinct banks
__global__ __launch_bounds__(256) void k_gemm2(const float* __restrict__ h,
                                               const float* __restrict__ W2,
                                               float* __restrict__ h2) {
    __shared__ float hs[64 * HS_STRIDE];   // 17.4 KB
    __shared__ float ws[FH * 64];          // 16 KB, cols 40..63 zero
    int t = threadIdx.x;
    int row0 = blockIdx.x * 64;
    {
        int r = t >> 4;              // 0..15
        int c4 = (t & 15) * 4;       // 0..60
#pragma unroll
        for (int p = 0; p < 4; ++p) {
            int row = row0 + r + p * 16;
            float4 v = make_float4(0.f, 0.f, 0.f, 0.f);
            if (row < NN) v = *(const float4*)&h[(size_t)row * FH + c4];
            *(float4*)&hs[(r + p * 16) * HS_STRIDE + c4] = v;
        }
    }
    for (int i = t; i < FH * 64; i += 256) {
        int r = i >> 6, c = i & 63;
        ws[i] = (c < FO) ? W2[r * FO + c] : 0.f;
    }
    __syncthreads();
    float acc[4][4] = {{0.f}};
    int tx4 = (t & 15) * 4;
    int ty4 = (t >> 4) * 4;
#pragma unroll 2
    for (int k = 0; k < FH; k += 4) {
        float4 a0 = *(const float4*)&hs[(ty4 + 0) * HS_STRIDE + k];
        float4 a1 = *(const float4*)&hs[(ty4 + 1) * HS_STRIDE + k];
        float4 a2 = *(const float4*)&hs[(ty4 + 2) * HS_STRIDE + k];
        float4 a3 = *(const float4*)&hs[(ty4 + 3) * HS_STRIDE + k];
        float4 b0 = *(const float4*)&ws[(k + 0) * 64 + tx4];
        float4 b1 = *(const float4*)&ws[(k + 1) * 64 + tx4];
        float4 b2 = *(const float4*)&ws[(k + 2) * 64 + tx4];
        float4 b3 = *(const float4*)&ws[(k + 3) * 64 + tx4];
#define KK2(AE, BV) \
        acc[0][0] = fmaf(a0.AE, BV.x, acc[0][0]); \
        acc[0][1] = fmaf(a0.AE, BV.y, acc[0][1]); \
        acc[0][2] = fmaf(a0.AE, BV.z, acc[0][2]); \
        acc[0][3] = fmaf(a0.AE, BV.w, acc[0][3]); \
        acc[1][0] = fmaf(a1.AE, BV.x, acc[1][0]); \
        acc[1][1] = fmaf(a1.AE, BV.y, acc[1][1]); \
        acc[1][2] = fmaf(a1.AE, BV.z, acc[1][2]); \
        acc[1][3] = fmaf(a1.AE, BV.w, acc[1][3]); \
        acc[2][0] = fmaf(a2.AE, BV.x, acc[2][0]); \
        acc[2][1] = fmaf(a2.AE, BV.y, acc[2][1]); \
        acc[2][2] = fmaf(a2.AE, BV.z, acc[2][2]); \
        acc[2][3] = fmaf(a2.AE, BV.w, acc[2][3]); \
        acc[3][0] = fmaf(a3.AE, BV.x, acc[3][0]); \
        acc[3][1] = fmaf(a3.AE, BV.y, acc[3][1]); \
        acc[3][2] = fmaf(a3.AE, BV.z, acc[3][2]); \
        acc[3][3] = fmaf(a3.AE, BV.w, acc[3][3]);
        KK2(x, b0) KK2(y, b1) KK2(z, b2) KK2(w, b3)
#undef KK2
    }
    if (tx4 < FO) {
#pragma unroll
        for (int i = 0; i < 4; ++i) {
            int row = row0 + ty4 + i;
            if (row < NN)
                *(float4*)&h2[(size_t)row * FO + tx4] =
                    make_float4(acc[i][0], acc[i][1], acc[i][2], acc[i][3]);
        }
    }
}

// ---------------- agg2: gather + self + b2 -> out --------------------------
__global__ __launch_bounds__(256) void k_agg2(const int* __restrict__ offs,
                                              const int* __restrict__ cnt,
                                              const int2* __restrict__ csr,
                                              const float* __restrict__ inv,
                                              const float* __restrict__ h2,
                                              const float* __restrict__ b2,
                                              float* __restrict__ out) {
    int lane = threadIdx.x & 63;
    int d = __builtin_amdgcn_readfirstlane((int)(blockIdx.x * 4 + (threadIdx.x >> 6)));
    if (d >= NN) return;
    int start = offs[d], deg = cnt[d];
    int c = (lane < FO) ? lane : 0;
    float acc = 0.f;
    int k = 0;
    for (; k + 2 <= deg; k += 2) {
        int2 sw0 = csr[start + k];
        int2 sw1 = csr[start + k + 1];
        float v0 = h2[(size_t)sw0.x * FO + c];
        float v1 = h2[(size_t)sw1.x * FO + c];
        acc = fmaf(v0, __int_as_float(sw0.y), acc);
        acc = fmaf(v1, __int_as_float(sw1.y), acc);
    }
    if (k < deg) {
        int2 sw = csr[start + k];
        acc = fmaf(h2[(size_t)sw.x * FO + c], __int_as_float(sw.y), acc);
    }
    if (lane < FO) {
        float invd = inv[d];
        out[(size_t)d * FO + lane] = (acc + h2[(size_t)d * FO + lane] * invd) * invd + b2[lane];
    }
}

extern "C" void kernel_launch(void* const* d_in, const int* in_sizes, int n_in,
                              void* d_out, int out_size, void* d_ws, size_t ws_size,
                              hipStream_t stream) {
    const float* x  = (const float*)d_in[0];
    const int*   ei = (const int*)d_in[1];   // int32 [2, NE]: src = ei[e], dst = ei[NE+e]
    const float* W1 = (const float*)d_in[2];
    const float* b1 = (const float*)d_in[3];
    const float* W2 = (const float*)d_in[4];
    const float* b2 = (const float*)d_in[5];
    float* out = (float*)d_out;

    char* ws = (char*)d_ws;
    int*   cnt   = (int*)ws;                              // 0.4 MB
    int*   offs  = (int*)(ws + (size_t)( 1 << 20));       // 0.4 MB
    int*   bsum  = (int*)(ws + (size_t)( 2 << 20));       // 1.6 KB
    float* inv   = (float*)(ws + (size_t)( 3 << 20));     // 0.4 MB
    int*   rank  = (int*)(ws + (size_t)( 4 << 20));       // 6.4 MB
    int2*  csr   = (int2*)(ws + (size_t)(11 << 20));      // 12.8 MB
    float* h0    = (float*)(ws + (size_t)(24 << 20));     // 25.6 MB
    float* h1    = (float*)(ws + (size_t)(50 << 20));     // 25.6 MB
    float* h2    = h0;                                    // reuse after agg1

    hipMemsetAsync(cnt, 0, NN * sizeof(int), stream);

    k_count<<<2048, 256, 0, stream>>>(ei, cnt, rank);
    k_scanA<<<NB, 256, 0, stream>>>(cnt, offs, bsum);
    k_scanB<<<1, 512, 0, stream>>>(bsum);
    k_scanC<<<NB, 256, 0, stream>>>(offs, bsum);
    k_inv<<<NB, 256, 0, stream>>>(cnt, inv);
    k_fill<<<2048, 256, 0, stream>>>(ei, rank, offs, inv, csr);

    int gblk = (NN + 63) / 64;   // 1563
    k_gemm1<<<gblk, 256, 0, stream>>>(x, W1, h0);
    k_agg1<<<NN / 4, 256, 0, stream>>>(offs, cnt, csr, inv, h0, b1, h1);

    k_gemm2<<<gblk, 256, 0, stream>>>(h1, W2, h2);
    k_agg2<<<NN / 4, 256, 0, stream>>>(offs, cnt, csr, inv, h2, b2, out);
}

// Round 10
// 280.136 us; speedup vs baseline: 3.6449x; 1.0857x over previous
//
#include <hip/hip_runtime.h>

#define NN 100000
#define NE 1600000
#define FI 128
#define FH 64
#define FO 40
#define NB ((NN + 255) / 256)   // 391 scan blocks

// ---------------- Threefry-2x32, key = (0, 42) -----------------------------
__device__ __forceinline__ unsigned rotl32(unsigned v, unsigned r) {
    return (v << r) | (v >> (32u - r));
}

__device__ __forceinline__ void threefry_0_42(unsigned x0, unsigned x1,
                                              unsigned& o0, unsigned& o1) {
    const unsigned k0 = 0u, k1 = 42u;
    const unsigned k2 = 0x1BD11BDAu ^ k0 ^ k1;
    x0 += k0; x1 += k1;
#define TFR(r) { x0 += x1; x1 = rotl32(x1, r); x1 ^= x0; }
    TFR(13) TFR(15) TFR(26) TFR(6)   x0 += k1; x1 += k2 + 1u;
    TFR(17) TFR(29) TFR(16) TFR(24)  x0 += k2; x1 += k0 + 2u;
    TFR(13) TFR(15) TFR(26) TFR(6)   x0 += k0; x1 += k1 + 3u;
    TFR(17) TFR(29) TFR(16) TFR(24)  x0 += k1; x1 += k2 + 4u;
    TFR(13) TFR(15) TFR(26) TFR(6)   x0 += k2; x1 += k0 + 5u;
#undef TFR
    o0 = x0; o1 = x1;
}

// ---------------- degree count + per-edge rank -----------------------------
__global__ __launch_bounds__(256) void k_count(const int* __restrict__ ei,
                                               int* __restrict__ cnt,
                                               int* __restrict__ rank) {
    int i = blockIdx.x * blockDim.x + threadIdx.x;
    int stride = gridDim.x * blockDim.x;
    for (; i < NE; i += stride) {
        rank[i] = atomicAdd(&cnt[ei[NE + i]], 1);  // rank within dst, coalesced store
    }
}

// ---------------- 3-kernel exclusive scan ----------------------------------
__global__ __launch_bounds__(256) void k_scanA(const int* __restrict__ cnt,
                                               int* __restrict__ offs,
                                               int* __restrict__ bsum) {
    __shared__ int sh[256];
    int t = threadIdx.x, g = blockIdx.x * 256 + t;
    int v = (g < NN) ? cnt[g] : 0;
    sh[t] = v;
    __syncthreads();
    for (int off = 1; off < 256; off <<= 1) {
        int u = (t >= off) ? sh[t - off] : 0;
        __syncthreads();
        sh[t] += u;
        __syncthreads();
    }
    if (g < NN) offs[g] = sh[t] - v;               // exclusive within block
    if (t == 255) bsum[blockIdx.x] = sh[255];      // block total
}

__global__ __launch_bounds__(512) void k_scanB(int* __restrict__ bsum) {
    __shared__ int sh[512];
    int t = threadIdx.x;
    int v = (t < NB) ? bsum[t] : 0;
    sh[t] = v;
    __syncthreads();
    for (int off = 1; off < 512; off <<= 1) {
        int u = (t >= off) ? sh[t - off] : 0;
        __syncthreads();
        sh[t] += u;
        __syncthreads();
    }
    if (t < NB) bsum[t] = sh[t] - v;               // exclusive block offsets
}

// scanC: finalize offs, pack (offs,cnt) for agg, compute inv
__global__ __launch_bounds__(256) void k_scanC(int* __restrict__ offs,
                                               const int* __restrict__ bsum,
                                               const int* __restrict__ cnt,
                                               int2* __restrict__ odpk,
                                               float* __restrict__ inv) {
    int g = blockIdx.x * 256 + threadIdx.x;
    if (g < NN) {
        int o = offs[g] + bsum[blockIdx.x];
        offs[g] = o;
        int c = cnt[g];
        odpk[g] = make_int2(o, c);
        inv[g] = rsqrtf((float)c + 1.0f);
    }
}

// ---------------- CSR fill: packed (src, w) single 8B store, no atomics ----
__global__ __launch_bounds__(256) void k_fill(const int* __restrict__ ei,
                                              const int* __restrict__ rank,
                                              const int* __restrict__ offs,
                                              const float* __restrict__ inv,
                                              int2* __restrict__ csr) {
    int i = blockIdx.x * blockDim.x + threadIdx.x;
    int stride = gridDim.x * blockDim.x;
    for (; i < NE; i += stride) {
        int s = ei[i];
        int d = ei[NE + i];
        int pos = offs[d] + rank[i];
        csr[pos] = make_int2(s, __float_as_int(inv[s]));
    }
}

// ---------------- GEMM1: h0[N,64] = x[N,128] @ W1[128,64] ------------------
#define XS_STRIDE 132   // 128 + 4: keeps b128 16B-aligned; rows on distinct banks
__global__ __launch_bounds__(256) void k_gemm1(const float* __restrict__ x,
                                               const float* __restrict__ W1,
                                               float* __restrict__ h0) {
    __shared__ float xs[64 * XS_STRIDE];   // 33.8 KB
    __shared__ float ws[64 * FH];          // 16 KB (one K-half of W1)
    int t = threadIdx.x;
    int row0 = blockIdx.x * 64;
    {
        int r = t >> 5;              // 0..7
        int c4 = (t & 31) * 4;       // 0..124
#pragma unroll
        for (int p = 0; p < 8; ++p) {
            int row = row0 + r + p * 8;
            float4 v = make_float4(0.f, 0.f, 0.f, 0.f);
            if (row < NN) v = *(const float4*)&x[(size_t)row * FI + c4];
            *(float4*)&xs[(r + p * 8) * XS_STRIDE + c4] = v;
        }
    }
    float acc[4][4] = {{0.f}};
    int tx4 = (t & 15) * 4;
    int ty4 = (t >> 4) * 4;
#pragma unroll
    for (int half = 0; half < 2; ++half) {
        __syncthreads();
        {
            const float4* Wv = (const float4*)(W1 + half * 64 * FH);
            float4* wv = (float4*)ws;
            for (int i = t; i < 64 * FH / 4; i += 256) wv[i] = Wv[i];
        }
        __syncthreads();
#pragma unroll 2
        for (int k = 0; k < 64; k += 4) {
            float4 a0 = *(const float4*)&xs[(ty4 + 0) * XS_STRIDE + half * 64 + k];
            float4 a1 = *(const float4*)&xs[(ty4 + 1) * XS_STRIDE + half * 64 + k];
            float4 a2 = *(const float4*)&xs[(ty4 + 2) * XS_STRIDE + half * 64 + k];
            float4 a3 = *(const float4*)&xs[(ty4 + 3) * XS_STRIDE + half * 64 + k];
            float4 b0 = *(const float4*)&ws[(k + 0) * FH + tx4];
            float4 b1 = *(const float4*)&ws[(k + 1) * FH + tx4];
            float4 b2 = *(const float4*)&ws[(k + 2) * FH + tx4];
            float4 b3 = *(const float4*)&ws[(k + 3) * FH + tx4];
#define KK1(AE, BV) \
            acc[0][0] = fmaf(a0.AE, BV.x, acc[0][0]); \
            acc[0][1] = fmaf(a0.AE, BV.y, acc[0][1]); \
            acc[0][2] = fmaf(a0.AE, BV.z, acc[0][2]); \
            acc[0][3] = fmaf(a0.AE, BV.w, acc[0][3]); \
            acc[1][0] = fmaf(a1.AE, BV.x, acc[1][0]); \
            acc[1][1] = fmaf(a1.AE, BV.y, acc[1][1]); \
            acc[1][2] = fmaf(a1.AE, BV.z, acc[1][2]); \
            acc[1][3] = fmaf(a1.AE, BV.w, acc[1][3]); \
            acc[2][0] = fmaf(a2.AE, BV.x, acc[2][0]); \
            acc[2][1] = fmaf(a2.AE, BV.y, acc[2][1]); \
            acc[2][2] = fmaf(a2.AE, BV.z, acc[2][2]); \
            acc[2][3] = fmaf(a2.AE, BV.w, acc[2][3]); \
            acc[3][0] = fmaf(a3.AE, BV.x, acc[3][0]); \
            acc[3][1] = fmaf(a3.AE, BV.y, acc[3][1]); \
            acc[3][2] = fmaf(a3.AE, BV.z, acc[3][2]); \
            acc[3][3] = fmaf(a3.AE, BV.w, acc[3][3]);
            KK1(x, b0) KK1(y, b1) KK1(z, b2) KK1(w, b3)
#undef KK1
        }
    }
#pragma unroll
    for (int i = 0; i < 4; ++i) {
        int row = row0 + ty4 + i;
        if (row < NN)
            *(float4*)&h0[(size_t)row * FH + tx4] =
                make_float4(acc[i][0], acc[i][1], acc[i][2], acc[i][3]);
    }
}

// ---------------- agg1: gather + self + bias + relu + dropout --------------
// 4-wide unrolled gather: one s_load_dwordx8 per group, 4 gathers in flight.
__global__ __launch_bounds__(256) void k_agg1(const int2* __restrict__ odpk,
                                              const int2* __restrict__ csr,
                                              const float* __restrict__ inv,
                                              const float* __restrict__ h0,
                                              const float* __restrict__ b1,
                                              float* __restrict__ h1) {
    int lane = threadIdx.x & 63;
    int d = __builtin_amdgcn_readfirstlane((int)(blockIdx.x * 4 + (threadIdx.x >> 6)));
    if (d >= NN) return;
    int2 od = odpk[d];
    int start = od.x, deg = od.y;
    float acc0 = 0.f, acc1 = 0.f;
    int k = 0;
    for (; k + 4 <= deg; k += 4) {
        int2 sw0 = csr[start + k + 0];
        int2 sw1 = csr[start + k + 1];
        int2 sw2 = csr[start + k + 2];
        int2 sw3 = csr[start + k + 3];
        float v0 = h0[(size_t)sw0.x * FH + lane];
        float v1 = h0[(size_t)sw1.x * FH + lane];
        float v2 = h0[(size_t)sw2.x * FH + lane];
        float v3 = h0[(size_t)sw3.x * FH + lane];
        acc0 = fmaf(v0, __int_as_float(sw0.y), acc0);
        acc1 = fmaf(v1, __int_as_float(sw1.y), acc1);
        acc0 = fmaf(v2, __int_as_float(sw2.y), acc0);
        acc1 = fmaf(v3, __int_as_float(sw3.y), acc1);
    }
    for (; k < deg; ++k) {
        int2 sw = csr[start + k];
        acc0 = fmaf(h0[(size_t)sw.x * FH + lane], __int_as_float(sw.y), acc0);
    }
    float acc = acc0 + acc1;
    float invd = inv[d];
    float val = (acc + h0[(size_t)d * FH + lane] * invd) * invd + b1[lane];
    val = fmaxf(val, 0.f);
    int i = d * FH + lane;
    unsigned o0, o1;
    threefry_0_42(0u, (unsigned)i, o0, o1);
    unsigned wbits = o0 ^ o1;            // partitionable f32 path: XOR fold
    h1[i] = (wbits >> 31) ? 0.f : val * 2.f;
}

// ---------------- GEMM2: h2[N,40] = h1[N,64] @ W2[64,40] -------------------
#define HS_STRIDE 68    // 64 + 4: b128-aligned, rows on distinct banks
__global__ __launch_bounds__(256) void k_gemm2(const float* __restrict__ h,
                                               const float* __restrict__ W2,
                                               float* __restrict__ h2) {
    __shared__ float hs[64 * HS_STRIDE];   // 17.4 KB
    __shared__ float ws[FH * 64];          // 16 KB, cols 40..63 zero
    int t = threadIdx.x;
    int row0 = blockIdx.x * 64;
    {
        int r = t >> 4;              // 0..15
        int c4 = (t & 15) * 4;       // 0..60
#pragma unroll
        for (int p = 0; p < 4; ++p) {
            int row = row0 + r + p * 16;
            float4 v = make_float4(0.f, 0.f, 0.f, 0.f);
            if (row < NN) v = *(const float4*)&h[(size_t)row * FH + c4];
            *(float4*)&hs[(r + p * 16) * HS_STRIDE + c4] = v;
        }
    }
    for (int i = t; i < FH * 64; i += 256) {
        int r = i >> 6, c = i & 63;
        ws[i] = (c < FO) ? W2[r * FO + c] : 0.f;
    }
    __syncthreads();
    float acc[4][4] = {{0.f}};
    int tx4 = (t & 15) * 4;
    int ty4 = (t >> 4) * 4;
#pragma unroll 2
    for (int k = 0; k < FH; k += 4) {
        float4 a0 = *(const float4*)&hs[(ty4 + 0) * HS_STRIDE + k];
        float4 a1 = *(const float4*)&hs[(ty4 + 1) * HS_STRIDE + k];
        float4 a2 = *(const float4*)&hs[(ty4 + 2) * HS_STRIDE + k];
        float4 a3 = *(const float4*)&hs[(ty4 + 3) * HS_STRIDE + k];
        float4 b0 = *(const float4*)&ws[(k + 0) * 64 + tx4];
        float4 b1 = *(const float4*)&ws[(k + 1) * 64 + tx4];
        float4 b2 = *(const float4*)&ws[(k + 2) * 64 + tx4];
        float4 b3 = *(const float4*)&ws[(k + 3) * 64 + tx4];
#define KK2(AE, BV) \
        acc[0][0] = fmaf(a0.AE, BV.x, acc[0][0]); \
        acc[0][1] = fmaf(a0.AE, BV.y, acc[0][1]); \
        acc[0][2] = fmaf(a0.AE, BV.z, acc[0][2]); \
        acc[0][3] = fmaf(a0.AE, BV.w, acc[0][3]); \
        acc[1][0] = fmaf(a1.AE, BV.x, acc[1][0]); \
        acc[1][1] = fmaf(a1.AE, BV.y, acc[1][1]); \
        acc[1][2] = fmaf(a1.AE, BV.z, acc[1][2]); \
        acc[1][3] = fmaf(a1.AE, BV.w, acc[1][3]); \
        acc[2][0] = fmaf(a2.AE, BV.x, acc[2][0]); \
        acc[2][1] = fmaf(a2.AE, BV.y, acc[2][1]); \
        acc[2][2] = fmaf(a2.AE, BV.z, acc[2][2]); \
        acc[2][3] = fmaf(a2.AE, BV.w, acc[2][3]); \
        acc[3][0] = fmaf(a3.AE, BV.x, acc[3][0]); \
        acc[3][1] = fmaf(a3.AE, BV.y, acc[3][1]); \
        acc[3][2] = fmaf(a3.AE, BV.z, acc[3][2]); \
        acc[3][3] = fmaf(a3.AE, BV.w, acc[3][3]);
        KK2(x, b0) KK2(y, b1) KK2(z, b2) KK2(w, b3)
#undef KK2
    }
    if (tx4 < FO) {
#pragma unroll
        for (int i = 0; i < 4; ++i) {
            int row = row0 + ty4 + i;
            if (row < NN)
                *(float4*)&h2[(size_t)row * FO + tx4] =
                    make_float4(acc[i][0], acc[i][1], acc[i][2], acc[i][3]);
        }
    }
}

// ---------------- agg2: gather + self + b2 -> out --------------------------
__global__ __launch_bounds__(256) void k_agg2(const int2* __restrict__ odpk,
                                              const int2* __restrict__ csr,
                                              const float* __restrict__ inv,
                                              const float* __restrict__ h2,
                                              const float* __restrict__ b2,
                                              float* __restrict__ out) {
    int lane = threadIdx.x & 63;
    int d = __builtin_amdgcn_readfirstlane((int)(blockIdx.x * 4 + (threadIdx.x >> 6)));
    if (d >= NN) return;
    int2 od = odpk[d];
    int start = od.x, deg = od.y;
    int c = (lane < FO) ? lane : 0;
    float acc0 = 0.f, acc1 = 0.f;
    int k = 0;
    for (; k + 4 <= deg; k += 4) {
        int2 sw0 = csr[start + k + 0];
        int2 sw1 = csr[start + k + 1];
        int2 sw2 = csr[start + k + 2];
        int2 sw3 = csr[start + k + 3];
        float v0 = h2[(size_t)sw0.x * FO + c];
        float v1 = h2[(size_t)sw1.x * FO + c];
        float v2 = h2[(size_t)sw2.x * FO + c];
        float v3 = h2[(size_t)sw3.x * FO + c];
        acc0 = fmaf(v0, __int_as_float(sw0.y), acc0);
        acc1 = fmaf(v1, __int_as_float(sw1.y), acc1);
        acc0 = fmaf(v2, __int_as_float(sw2.y), acc0);
        acc1 = fmaf(v3, __int_as_float(sw3.y), acc1);
    }
    for (; k < deg; ++k) {
        int2 sw = csr[start + k];
        acc0 = fmaf(h2[(size_t)sw.x * FO + c], __int_as_float(sw.y), acc0);
    }
    if (lane < FO) {
        float invd = inv[d];
        out[(size_t)d * FO + lane] =
            (acc0 + acc1 + h2[(size_t)d * FO + lane] * invd) * invd + b2[lane];
    }
}

extern "C" void kernel_launch(void* const* d_in, const int* in_sizes, int n_in,
                              void* d_out, int out_size, void* d_ws, size_t ws_size,
                              hipStream_t stream) {
    const float* x  = (const float*)d_in[0];
    const int*   ei = (const int*)d_in[1];   // int32 [2, NE]: src = ei[e], dst = ei[NE+e]
    const float* W1 = (const float*)d_in[2];
    const float* b1 = (const float*)d_in[3];
    const float* W2 = (const float*)d_in[4];
    const float* b2 = (const float*)d_in[5];
    float* out = (float*)d_out;

    char* ws = (char*)d_ws;
    int*   cnt   = (int*)ws;                              // 0.4 MB
    int*   offs  = (int*)(ws + (size_t)( 1 << 20));       // 0.4 MB
    int*   bsum  = (int*)(ws + (size_t)( 2 << 20));       // 1.6 KB
    float* inv   = (float*)(ws + (size_t)( 3 << 20));     // 0.4 MB
    int2*  odpk  = (int2*)(ws + (size_t)( 4 << 20));      // 0.8 MB
    int*   rank  = (int*)(ws + (size_t)( 5 << 20));       // 6.4 MB
    int2*  csr   = (int2*)(ws + (size_t)(12 << 20));      // 12.8 MB
    float* h0    = (float*)(ws + (size_t)(25 << 20));     // 25.6 MB
    float* h1    = (float*)(ws + (size_t)(51 << 20));     // 25.6 MB
    float* h2    = h0;                                    // reuse after agg1

    hipMemsetAsync(cnt, 0, NN * sizeof(int), stream);

    k_count<<<2048, 256, 0, stream>>>(ei, cnt, rank);
    k_scanA<<<NB, 256, 0, stream>>>(cnt, offs, bsum);
    k_scanB<<<1, 512, 0, stream>>>(bsum);
    k_scanC<<<NB, 256, 0, stream>>>(offs, bsum, cnt, odpk, inv);
    k_fill<<<2048, 256, 0, stream>>>(ei, rank, offs, inv, csr);

    int gblk = (NN + 63) / 64;   // 1563
    k_gemm1<<<gblk, 256, 0, stream>>>(x, W1, h0);
    k_agg1<<<NN / 4, 256, 0, stream>>>(odpk, csr, inv, h0, b1, h1);

    k_gemm2<<<gblk, 256, 0, stream>>>(h1, W2, h2);
    k_agg2<<<NN / 4, 256, 0, stream>>>(odpk, csr, inv, h2, b2, out);
}

// Round 11
// 259.584 us; speedup vs baseline: 3.9334x; 1.0792x over previous
//
#include <hip/hip_runtime.h>

#define NN 100000
#define NE 1600000
#define FI 128
#define FH 64
#define FO 40
#define NB ((NN + 255) / 256)   // 391 scan blocks

typedef _Float16 f16;

// ---------------- Threefry-2x32, key = (0, 42) -----------------------------
__device__ __forceinline__ unsigned rotl32(unsigned v, unsigned r) {
    return (v << r) | (v >> (32u - r));
}

__device__ __forceinline__ void threefry_0_42(unsigned x0, unsigned x1,
                                              unsigned& o0, unsigned& o1) {
    const unsigned k0 = 0u, k1 = 42u;
    const unsigned k2 = 0x1BD11BDAu ^ k0 ^ k1;
    x0 += k0; x1 += k1;
#define TFR(r) { x0 += x1; x1 = rotl32(x1, r); x1 ^= x0; }
    TFR(13) TFR(15) TFR(26) TFR(6)   x0 += k1; x1 += k2 + 1u;
    TFR(17) TFR(29) TFR(16) TFR(24)  x0 += k2; x1 += k0 + 2u;
    TFR(13) TFR(15) TFR(26) TFR(6)   x0 += k0; x1 += k1 + 3u;
    TFR(17) TFR(29) TFR(16) TFR(24)  x0 += k1; x1 += k2 + 4u;
    TFR(13) TFR(15) TFR(26) TFR(6)   x0 += k2; x1 += k0 + 5u;
#undef TFR
    o0 = x0; o1 = x1;
}

// ---------------- degree count + per-edge rank (4-wide unroll) -------------
__global__ __launch_bounds__(256) void k_count(const int* __restrict__ ei,
                                               int* __restrict__ cnt,
                                               int* __restrict__ rank) {
    int i = blockIdx.x * blockDim.x + threadIdx.x;
    int stride = gridDim.x * blockDim.x;
    for (; i + 3 * stride < NE; i += 4 * stride) {
        int d0 = ei[NE + i];
        int d1 = ei[NE + i + stride];
        int d2 = ei[NE + i + 2 * stride];
        int d3 = ei[NE + i + 3 * stride];
        int r0 = atomicAdd(&cnt[d0], 1);
        int r1 = atomicAdd(&cnt[d1], 1);
        int r2 = atomicAdd(&cnt[d2], 1);
        int r3 = atomicAdd(&cnt[d3], 1);
        rank[i] = r0;
        rank[i + stride] = r1;
        rank[i + 2 * stride] = r2;
        rank[i + 3 * stride] = r3;
    }
    for (; i < NE; i += stride) rank[i] = atomicAdd(&cnt[ei[NE + i]], 1);
}

// ---------------- 3-kernel exclusive scan ----------------------------------
__global__ __launch_bounds__(256) void k_scanA(const int* __restrict__ cnt,
                                               int* __restrict__ offs,
                                               int* __restrict__ bsum) {
    __shared__ int sh[256];
    int t = threadIdx.x, g = blockIdx.x * 256 + t;
    int v = (g < NN) ? cnt[g] : 0;
    sh[t] = v;
    __syncthreads();
    for (int off = 1; off < 256; off <<= 1) {
        int u = (t >= off) ? sh[t - off] : 0;
        __syncthreads();
        sh[t] += u;
        __syncthreads();
    }
    if (g < NN) offs[g] = sh[t] - v;               // exclusive within block
    if (t == 255) bsum[blockIdx.x] = sh[255];      // block total
}

__global__ __launch_bounds__(512) void k_scanB(int* __restrict__ bsum) {
    __shared__ int sh[512];
    int t = threadIdx.x;
    int v = (t < NB) ? bsum[t] : 0;
    sh[t] = v;
    __syncthreads();
    for (int off = 1; off < 512; off <<= 1) {
        int u = (t >= off) ? sh[t - off] : 0;
        __syncthreads();
        sh[t] += u;
        __syncthreads();
    }
    if (t < NB) bsum[t] = sh[t] - v;               // exclusive block offsets
}

// scanC: finalize offs, pack (offs,cnt) for agg, compute inv
__global__ __launch_bounds__(256) void k_scanC(int* __restrict__ offs,
                                               const int* __restrict__ bsum,
                                               const int* __restrict__ cnt,
                                               int2* __restrict__ odpk,
                                               float* __restrict__ inv) {
    int g = blockIdx.x * 256 + threadIdx.x;
    if (g < NN) {
        int o = offs[g] + bsum[blockIdx.x];
        offs[g] = o;
        int c = cnt[g];
        odpk[g] = make_int2(o, c);
        inv[g] = rsqrtf((float)c + 1.0f);
    }
}

// ---------------- CSR fill: src index only, 4B scattered store -------------
__global__ __launch_bounds__(256) void k_fill(const int* __restrict__ ei,
                                              const int* __restrict__ rank,
                                              const int* __restrict__ offs,
                                              int* __restrict__ csr_s) {
    int i = blockIdx.x * blockDim.x + threadIdx.x;
    int stride = gridDim.x * blockDim.x;
    for (; i < NE; i += stride) {
        int s = ei[i];
        int d = ei[NE + i];
        csr_s[offs[d] + rank[i]] = s;
    }
}

// ---------------- GEMM1: h0s[N,64] = (x[N,128] @ W1) * inv[row]  (fp16) ----
#define XS_STRIDE 132   // 128 + 4: keeps b128 16B-aligned; rows on distinct banks
__global__ __launch_bounds__(256) void k_gemm1(const float* __restrict__ x,
                                               const float* __restrict__ W1,
                                               const float* __restrict__ inv,
                                               f16* __restrict__ h0s) {
    __shared__ float xs[64 * XS_STRIDE];   // 33.8 KB
    __shared__ float ws[64 * FH];          // 16 KB (one K-half of W1)
    int t = threadIdx.x;
    int row0 = blockIdx.x * 64;
    {
        int r = t >> 5;              // 0..7
        int c4 = (t & 31) * 4;       // 0..124
#pragma unroll
        for (int p = 0; p < 8; ++p) {
            int row = row0 + r + p * 8;
            float4 v = make_float4(0.f, 0.f, 0.f, 0.f);
            if (row < NN) v = *(const float4*)&x[(size_t)row * FI + c4];
            *(float4*)&xs[(r + p * 8) * XS_STRIDE + c4] = v;
        }
    }
    float acc[4][4] = {{0.f}};
    int tx4 = (t & 15) * 4;
    int ty4 = (t >> 4) * 4;
#pragma unroll
    for (int half = 0; half < 2; ++half) {
        __syncthreads();
        {
            const float4* Wv = (const float4*)(W1 + half * 64 * FH);
            float4* wv = (float4*)ws;
            for (int i = t; i < 64 * FH / 4; i += 256) wv[i] = Wv[i];
        }
        __syncthreads();
#pragma unroll 2
        for (int k = 0; k < 64; k += 4) {
            float4 a0 = *(const float4*)&xs[(ty4 + 0) * XS_STRIDE + half * 64 + k];
            float4 a1 = *(const float4*)&xs[(ty4 + 1) * XS_STRIDE + half * 64 + k];
            float4 a2 = *(const float4*)&xs[(ty4 + 2) * XS_STRIDE + half * 64 + k];
            float4 a3 = *(const float4*)&xs[(ty4 + 3) * XS_STRIDE + half * 64 + k];
            float4 b0 = *(const float4*)&ws[(k + 0) * FH + tx4];
            float4 b1 = *(const float4*)&ws[(k + 1) * FH + tx4];
            float4 b2 = *(const float4*)&ws[(k + 2) * FH + tx4];
            float4 b3 = *(const float4*)&ws[(k + 3) * FH + tx4];
#define KK1(AE, BV) \
            acc[0][0] = fmaf(a0.AE, BV.x, acc[0][0]); \
            acc[0][1] = fmaf(a0.AE, BV.y, acc[0][1]); \
            acc[0][2] = fmaf(a0.AE, BV.z, acc[0][2]); \
            acc[0][3] = fmaf(a0.AE, BV.w, acc[0][3]); \
            acc[1][0] = fmaf(a1.AE, BV.x, acc[1][0]); \
            acc[1][1] = fmaf(a1.AE, BV.y, acc[1][1]); \
            acc[1][2] = fmaf(a1.AE, BV.z, acc[1][2]); \
            acc[1][3] = fmaf(a1.AE, BV.w, acc[1][3]); \
            acc[2][0] = fmaf(a2.AE, BV.x, acc[2][0]); \
            acc[2][1] = fmaf(a2.AE, BV.y, acc[2][1]); \
            acc[2][2] = fmaf(a2.AE, BV.z, acc[2][2]); \
            acc[2][3] = fmaf(a2.AE, BV.w, acc[2][3]); \
            acc[3][0] = fmaf(a3.AE, BV.x, acc[3][0]); \
            acc[3][1] = fmaf(a3.AE, BV.y, acc[3][1]); \
            acc[3][2] = fmaf(a3.AE, BV.z, acc[3][2]); \
            acc[3][3] = fmaf(a3.AE, BV.w, acc[3][3]);
            KK1(x, b0) KK1(y, b1) KK1(z, b2) KK1(w, b3)
#undef KK1
        }
    }
#pragma unroll
    for (int i = 0; i < 4; ++i) {
        int row = row0 + ty4 + i;
        if (row < NN) {
            float s = inv[row];
            union { f16 h[4]; uint2 u; } p;
            p.h[0] = (f16)(acc[i][0] * s);
            p.h[1] = (f16)(acc[i][1] * s);
            p.h[2] = (f16)(acc[i][2] * s);
            p.h[3] = (f16)(acc[i][3] * s);
            *(uint2*)&h0s[(size_t)row * FH + tx4] = p.u;
        }
    }
}

// ---------------- agg1: gather(fp16) + self + bias + relu + dropout --------
__global__ __launch_bounds__(256) void k_agg1(const int2* __restrict__ odpk,
                                              const int* __restrict__ csr_s,
                                              const float* __restrict__ inv,
                                              const f16* __restrict__ h0s,
                                              const float* __restrict__ b1,
                                              float* __restrict__ h1) {
    int lane = threadIdx.x & 63;
    int d = __builtin_amdgcn_readfirstlane((int)(blockIdx.x * 4 + (threadIdx.x >> 6)));
    if (d >= NN) return;
    int2 od = odpk[d];
    int start = od.x, deg = od.y;
    float acc0 = 0.f, acc1 = 0.f;
    int k = 0;
    for (; k + 4 <= deg; k += 4) {
        int s0 = csr_s[start + k + 0];
        int s1 = csr_s[start + k + 1];
        int s2 = csr_s[start + k + 2];
        int s3 = csr_s[start + k + 3];
        float v0 = (float)h0s[(size_t)s0 * FH + lane];
        float v1 = (float)h0s[(size_t)s1 * FH + lane];
        float v2 = (float)h0s[(size_t)s2 * FH + lane];
        float v3 = (float)h0s[(size_t)s3 * FH + lane];
        acc0 += v0 + v2;
        acc1 += v1 + v3;
    }
    for (; k < deg; ++k) {
        int s = csr_s[start + k];
        acc0 += (float)h0s[(size_t)s * FH + lane];
    }
    float invd = inv[d];
    float val = (acc0 + acc1 + (float)h0s[(size_t)d * FH + lane]) * invd + b1[lane];
    val = fmaxf(val, 0.f);
    int i = d * FH + lane;
    unsigned o0, o1;
    threefry_0_42(0u, (unsigned)i, o0, o1);
    unsigned wbits = o0 ^ o1;            // partitionable f32 path: XOR fold
    h1[i] = (wbits >> 31) ? 0.f : val * 2.f;
}

// ---------------- GEMM2: h2s[N,64(pad)] = (h1 @ W2) * inv[row]  (fp16) -----
#define HS_STRIDE 68    // 64 + 4: b128-aligned, rows on distinct banks
__global__ __launch_bounds__(256) void k_gemm2(const float* __restrict__ h,
                                               const float* __restrict__ W2,
                                               const float* __restrict__ inv,
                                               f16* __restrict__ h2s) {
    __shared__ float hs[64 * HS_STRIDE];   // 17.4 KB
    __shared__ float ws[FH * 64];          // 16 KB, cols 40..63 zero
    int t = threadIdx.x;
    int row0 = blockIdx.x * 64;
    {
        int r = t >> 4;              // 0..15
        int c4 = (t & 15) * 4;       // 0..60
#pragma unroll
        for (int p = 0; p < 4; ++p) {
            int row = row0 + r + p * 16;
            float4 v = make_float4(0.f, 0.f, 0.f, 0.f);
            if (row < NN) v = *(const float4*)&h[(size_t)row * FH + c4];
            *(float4*)&hs[(r + p * 16) * HS_STRIDE + c4] = v;
        }
    }
    for (int i = t; i < FH * 64; i += 256) {
        int r = i >> 6, c = i & 63;
        ws[i] = (c < FO) ? W2[r * FO + c] : 0.f;
    }
    __syncthreads();
    float acc[4][4] = {{0.f}};
    int tx4 = (t & 15) * 4;
    int ty4 = (t >> 4) * 4;
#pragma unroll 2
    for (int k = 0; k < FH; k += 4) {
        float4 a0 = *(const float4*)&hs[(ty4 + 0) * HS_STRIDE + k];
        float4 a1 = *(const float4*)&hs[(ty4 + 1) * HS_STRIDE + k];
        float4 a2 = *(const float4*)&hs[(ty4 + 2) * HS_STRIDE + k];
        float4 a3 = *(const float4*)&hs[(ty4 + 3) * HS_STRIDE + k];
        float4 b0 = *(const float4*)&ws[(k + 0) * 64 + tx4];
        float4 b1 = *(const float4*)&ws[(k + 1) * 64 + tx4];
        float4 b2 = *(const float4*)&ws[(k + 2) * 64 + tx4];
        float4 b3 = *(const float4*)&ws[(k + 3) * 64 + tx4];
#define KK2(AE, BV) \
        acc[0][0] = fmaf(a0.AE, BV.x, acc[0][0]); \
        acc[0][1] = fmaf(a0.AE, BV.y, acc[0][1]); \
        acc[0][2] = fmaf(a0.AE, BV.z, acc[0][2]); \
        acc[0][3] = fmaf(a0.AE, BV.w, acc[0][3]); \
        acc[1][0] = fmaf(a1.AE, BV.x, acc[1][0]); \
        acc[1][1] = fmaf(a1.AE, BV.y, acc[1][1]); \
        acc[1][2] = fmaf(a1.AE, BV.z, acc[1][2]); \
        acc[1][3] = fmaf(a1.AE, BV.w, acc[1][3]); \
        acc[2][0] = fmaf(a2.AE, BV.x, acc[2][0]); \
        acc[2][1] = fmaf(a2.AE, BV.y, acc[2][1]); \
        acc[2][2] = fmaf(a2.AE, BV.z, acc[2][2]); \
        acc[2][3] = fmaf(a2.AE, BV.w, acc[2][3]); \
        acc[3][0] = fmaf(a3.AE, BV.x, acc[3][0]); \
        acc[3][1] = fmaf(a3.AE, BV.y, acc[3][1]); \
        acc[3][2] = fmaf(a3.AE, BV.z, acc[3][2]); \
        acc[3][3] = fmaf(a3.AE, BV.w, acc[3][3]);
        KK2(x, b0) KK2(y, b1) KK2(z, b2) KK2(w, b3)
#undef KK2
    }
#pragma unroll
    for (int i = 0; i < 4; ++i) {
        int row = row0 + ty4 + i;
        if (row < NN) {
            float s = inv[row];
            union { f16 h[4]; uint2 u; } p;
            p.h[0] = (f16)(acc[i][0] * s);
            p.h[1] = (f16)(acc[i][1] * s);
            p.h[2] = (f16)(acc[i][2] * s);
            p.h[3] = (f16)(acc[i][3] * s);   // cols >= 40 are garbage*0? no: ws cols >=40 are 0 -> acc 0
            *(uint2*)&h2s[(size_t)row * FH + tx4] = p.u;
        }
    }
}

// ---------------- agg2: gather(fp16) + self + b2 -> out --------------------
__global__ __launch_bounds__(256) void k_agg2(const int2* __restrict__ odpk,
                                              const int* __restrict__ csr_s,
                                              const float* __restrict__ inv,
                                              const f16* __restrict__ h2s,
                                              const float* __restrict__ b2,
                                              float* __restrict__ out) {
    int lane = threadIdx.x & 63;
    int d = __builtin_amdgcn_readfirstlane((int)(blockIdx.x * 4 + (threadIdx.x >> 6)));
    if (d >= NN) return;
    int2 od = odpk[d];
    int start = od.x, deg = od.y;
    float acc0 = 0.f, acc1 = 0.f;
    int k = 0;
    for (; k + 4 <= deg; k += 4) {
        int s0 = csr_s[start + k + 0];
        int s1 = csr_s[start + k + 1];
        int s2 = csr_s[start + k + 2];
        int s3 = csr_s[start + k + 3];
        float v0 = (float)h2s[(size_t)s0 * FH + lane];
        float v1 = (float)h2s[(size_t)s1 * FH + lane];
        float v2 = (float)h2s[(size_t)s2 * FH + lane];
        float v3 = (float)h2s[(size_t)s3 * FH + lane];
        acc0 += v0 + v2;
        acc1 += v1 + v3;
    }
    for (; k < deg; ++k) {
        int s = csr_s[start + k];
        acc0 += (float)h2s[(size_t)s * FH + lane];
    }
    if (lane < FO) {
        float invd = inv[d];
        out[(size_t)d * FO + lane] =
            (acc0 + acc1 + (float)h2s[(size_t)d * FH + lane]) * invd + b2[lane];
    }
}

extern "C" void kernel_launch(void* const* d_in, const int* in_sizes, int n_in,
                              void* d_out, int out_size, void* d_ws, size_t ws_size,
                              hipStream_t stream) {
    const float* x  = (const float*)d_in[0];
    const int*   ei = (const int*)d_in[1];   // int32 [2, NE]: src = ei[e], dst = ei[NE+e]
    const float* W1 = (const float*)d_in[2];
    const float* b1 = (const float*)d_in[3];
    const float* W2 = (const float*)d_in[4];
    const float* b2 = (const float*)d_in[5];
    float* out = (float*)d_out;

    char* ws = (char*)d_ws;
    int*   cnt   = (int*)ws;                              // 0.4 MB
    int*   offs  = (int*)(ws + (size_t)( 1 << 20));       // 0.4 MB
    int*   bsum  = (int*)(ws + (size_t)( 2 << 20));       // 1.6 KB
    float* inv   = (float*)(ws + (size_t)( 3 << 20));     // 0.4 MB
    int2*  odpk  = (int2*)(ws + (size_t)( 4 << 20));      // 0.8 MB
    int*   rank  = (int*)(ws + (size_t)( 5 << 20));       // 6.4 MB
    int*   csr_s = (int*)(ws + (size_t)(12 << 20));       // 6.4 MB
    f16*   h0s   = (f16*)(ws + (size_t)(19 << 20));       // 12.8 MB
    float* h1    = (float*)(ws + (size_t)(32 << 20));     // 25.6 MB
    f16*   h2s   = (f16*)(ws + (size_t)(58 << 20));       // 12.8 MB

    hipMemsetAsync(cnt, 0, NN * sizeof(int), stream);

    k_count<<<1024, 256, 0, stream>>>(ei, cnt, rank);
    k_scanA<<<NB, 256, 0, stream>>>(cnt, offs, bsum);
    k_scanB<<<1, 512, 0, stream>>>(bsum);
    k_scanC<<<NB, 256, 0, stream>>>(offs, bsum, cnt, odpk, inv);
    k_fill<<<2048, 256, 0, stream>>>(ei, rank, offs, csr_s);

    int gblk = (NN + 63) / 64;   // 1563
    k_gemm1<<<gblk, 256, 0, stream>>>(x, W1, inv, h0s);
    k_agg1<<<NN / 4, 256, 0, stream>>>(odpk, csr_s, inv, h0s, b1, h1);

    k_gemm2<<<gblk, 256, 0, stream>>>(h1, W2, inv, h2s);
    k_agg2<<<NN / 4, 256, 0, stream>>>(odpk, csr_s, inv, h2s, b2, out);
}